// Round 15
// baseline (186.806 us; speedup 1.0000x reference)
//
#include <hip/hip_runtime.h>

// ---------------- problem constants ----------------
#define BB   8
#define KQ   64
#define HDIM 2048
#define NH   16
#define NKV  4
#define HD   128
#define CTX  4096
#define TTOT 4160      // CTX + KQ
#define NTILES 65      // TTOT / 64
#define LOG2E 1.4426950408889634f
#define SCALE 0.08838834764831845f  // 1/sqrt(128)
#define QSCALE (SCALE * LOG2E)      // folded into Q; exp2-domain softmax
// |q.k| <= 128 after RMS-norm => |sc| <= 128*QSCALE = 16.33. Fixed softmax max.
#define MFIX 16.34f

typedef unsigned short u16;
typedef unsigned int   u32;
typedef __attribute__((ext_vector_type(8))) short  s16x8;   // bf16 storage
typedef __attribute__((ext_vector_type(4))) unsigned short u16x4;
typedef __attribute__((ext_vector_type(4))) float  f32x4;
typedef __bf16 bf16x8 __attribute__((ext_vector_type(8)));  // MFMA operand

__device__ __forceinline__ u16 f2bf(float f) {              // HW RNE cvt
    union { __bf16 h; u16 u; } v; v.h = (__bf16)f; return v.u;
}
__device__ __forceinline__ float bf2f(u16 u) {
    union { float f; u32 u; } v; v.u = ((u32)u) << 16;
    return v.f;
}
__device__ __forceinline__ u32 pack2(float a, float b) {
    return (u32)f2bf(a) | ((u32)f2bf(b) << 16);
}
__device__ __forceinline__ f32x4 mfma16(bf16x8 a, bf16x8 b, f32x4 c) {
    return __builtin_amdgcn_mfma_f32_16x16x32_bf16(a, b, c, 0, 0, 0);
}

// ---------------- fused f32 -> bf16 cast of 5 tensors + cos/sin tables ----
__global__ __launch_bounds__(256) void cast_all(
    const float* __restrict__ wq, const float* __restrict__ wk,
    const float* __restrict__ wv, const float* __restrict__ wo,
    const float* __restrict__ hs, const float* __restrict__ cosT,
    const float* __restrict__ sinT,
    u16* __restrict__ wqkvb, u16* __restrict__ wob, u16* __restrict__ hsb,
    u16* __restrict__ cosb, u16* __restrict__ sinb)
{
    const int i = blockIdx.x * 256 + threadIdx.x;
    const float* src; u16* dst;
    if (i < 524288)        { src = wq + (size_t)i * 8;             dst = wqkvb + (size_t)i * 8; }
    else if (i < 655360)   { src = wk + (size_t)(i - 524288) * 8;  dst = wqkvb + (size_t)i * 8; }
    else if (i < 786432)   { src = wv + (size_t)(i - 655360) * 8;  dst = wqkvb + (size_t)i * 8; }
    else if (i < 1310720)  { src = wo + (size_t)(i - 786432) * 8;  dst = wob + (size_t)(i - 786432) * 8; }
    else if (i < 1441792)  { src = hs + (size_t)(i - 1310720) * 8; dst = hsb + (size_t)(i - 1310720) * 8; }
    else if (i < 1475072)  { const int l = (i - 1441792) * 8;
                             src = cosT + (size_t)(l >> 6) * 128 + (l & 63); dst = cosb + l; }
    else                   { const int l = (i - 1475072) * 8;
                             src = sinT + (size_t)(l >> 6) * 128 + (l & 63); dst = sinb + l; }
    float4 a = *(const float4*)src;
    float4 b = *(const float4*)(src + 4);
    s16x8 v;
    v[0]=(short)f2bf(a.x); v[1]=(short)f2bf(a.y); v[2]=(short)f2bf(a.z); v[3]=(short)f2bf(a.w);
    v[4]=(short)f2bf(b.x); v[5]=(short)f2bf(b.y); v[6]=(short)f2bf(b.z); v[7]=(short)f2bf(b.w);
    *(s16x8*)dst = v;
}

// ---------------- mask pre-transpose: maskT[b][pos][q] bf16 ---------------
__global__ __launch_bounds__(256) void prep_mask(
    const float* __restrict__ mask, u16* __restrict__ maskT)
{
    __shared__ float T[64 * 65];
    const int pt = blockIdx.x % 65, b = blockIdx.x / 65;
    const int p0 = pt * 64;
    {
        const int q = threadIdx.x >> 2, pg = (threadIdx.x & 3) * 16;
        const float* src = mask + ((size_t)b * 64 + q) * TTOT + p0 + pg;
#pragma unroll
        for (int v4 = 0; v4 < 4; ++v4) {
            float4 v = *(const float4*)(src + v4 * 4);
            T[q * 65 + pg + v4 * 4 + 0] = fmaf(v.x, LOG2E, -MFIX);
            T[q * 65 + pg + v4 * 4 + 1] = fmaf(v.y, LOG2E, -MFIX);
            T[q * 65 + pg + v4 * 4 + 2] = fmaf(v.z, LOG2E, -MFIX);
            T[q * 65 + pg + v4 * 4 + 3] = fmaf(v.w, LOG2E, -MFIX);
        }
    }
    __syncthreads();
    {
        const int pos = threadIdx.x >> 2, qg = (threadIdx.x & 3) * 16;
        u16* dst = maskT + ((size_t)b * TTOT + p0 + pos) * 64 + qg;
#pragma unroll
        for (int h8 = 0; h8 < 2; ++h8) {
            s16x8 v;
#pragma unroll
            for (int je = 0; je < 8; ++je)
                v[je] = (short)f2bf(T[(qg + h8 * 8 + je) * 65 + pos]);
            *(s16x8*)(dst + h8 * 8) = v;
        }
    }
}

// ---------------- 64x64-tile GEMM core, bf16 inputs (padded LDS) ----------
__device__ __forceinline__ void gemm64_body(
    const u16* __restrict__ Ab, const u16* __restrict__ Bb,
    float* __restrict__ Cb, const int ldc, const int ldk, const int Klen,
    u16* Ash, u16* Bsh)
{
    const int tid = threadIdx.x, lane = tid & 63;
    const int w = tid >> 6, wm = w >> 1, wn = w & 1;
    const int l15 = lane & 15, l4 = lane >> 4;
    const int srow = tid >> 2, scol = (tid & 3) * 16;

    f32x4 acc[2][2];
#pragma unroll
    for (int i = 0; i < 2; ++i)
#pragma unroll
        for (int j = 0; j < 2; ++j) acc[i][j] = (f32x4){0.f, 0.f, 0.f, 0.f};

    const u16* ap = Ab + (size_t)srow * ldk + scol;
    const u16* bp = Bb + (size_t)srow * ldk + scol;
    s16x8 ra0 = *(const s16x8*)ap, ra1 = *(const s16x8*)(ap + 8);
    s16x8 rb0 = *(const s16x8*)bp, rb1 = *(const s16x8*)(bp + 8);
    __builtin_amdgcn_sched_barrier(0);

    for (int k0 = 0; k0 < Klen; k0 += 64) {
        __syncthreads();
        *(s16x8*)(Ash + srow * 72 + scol)     = ra0;
        *(s16x8*)(Ash + srow * 72 + scol + 8) = ra1;
        *(s16x8*)(Bsh + srow * 72 + scol)     = rb0;
        *(s16x8*)(Bsh + srow * 72 + scol + 8) = rb1;
        __syncthreads();
        if (k0 + 64 < Klen) {
            const u16* ap2 = ap + k0 + 64;
            const u16* bp2 = bp + k0 + 64;
            ra0 = *(const s16x8*)ap2; ra1 = *(const s16x8*)(ap2 + 8);
            rb0 = *(const s16x8*)bp2; rb1 = *(const s16x8*)(bp2 + 8);
            __builtin_amdgcn_sched_barrier(0);
        }
#pragma unroll
        for (int ks = 0; ks < 2; ++ks) {
            bf16x8 am[2], bb[2];
#pragma unroll
            for (int i = 0; i < 2; ++i) {
                am[i] = *(const bf16x8*)(Ash + (wm * 32 + i * 16 + l15) * 72 + ks * 32 + l4 * 8);
                bb[i] = *(const bf16x8*)(Bsh + (wn * 32 + i * 16 + l15) * 72 + ks * 32 + l4 * 8);
            }
#pragma unroll
            for (int i = 0; i < 2; ++i)
#pragma unroll
                for (int j = 0; j < 2; ++j)
                    acc[i][j] = mfma16(am[i], bb[j], acc[i][j]);
        }
    }

    float* Cw = Cb + (size_t)(wm * 32) * ldc + wn * 32;
#pragma unroll
    for (int i = 0; i < 2; ++i)
#pragma unroll
        for (int j = 0; j < 2; ++j)
#pragma unroll
            for (int r = 0; r < 4; ++r)
                Cw[(size_t)(i * 16 + l4 * 4 + r) * ldc + j * 16 + l15] = acc[i][j][r];
}

// QKV projection, split-K x4, XCD-chunked swizzle. 1D grid 1536.
__global__ __launch_bounds__(256) void gemm_qkv_sk(
    const u16* __restrict__ hsb, const u16* __restrict__ wqkvb,
    float* __restrict__ qkvp)
{
    __shared__ __align__(16) u16 Ash[64 * 72];
    __shared__ __align__(16) u16 Bsh[64 * 72];
    const int wid = (blockIdx.x & 7) * 192 + (blockIdx.x >> 3);
    const int y = wid >> 5, rem = wid & 31, kc = rem >> 3, x = rem & 7;
    const int koff = kc * 512;
    const u16* Ab = hsb + (size_t)x * 64 * HDIM + koff;
    const u16* Bb = wqkvb + (size_t)y * 64 * HDIM + koff;
    float* Cb = qkvp + (size_t)kc * 512 * 3072 + (size_t)x * 64 * 3072 + y * 64;
    gemm64_body(Ab, Bb, Cb, 3072, HDIM, 512, Ash, Bsh);
}

// Output projection, split-K x4, XCD-chunked swizzle. 1D grid 1024.
__global__ __launch_bounds__(256) void gemm_out_sk(
    const u16* __restrict__ attnb, const u16* __restrict__ wob,
    float* __restrict__ outp)
{
    __shared__ __align__(16) u16 Ash[64 * 72];
    __shared__ __align__(16) u16 Bsh[64 * 72];
    const int wid = (blockIdx.x & 7) * 128 + (blockIdx.x >> 3);
    const int y = wid >> 5, rem = wid & 31, kc = rem >> 3, x = rem & 7;
    const int koff = kc * 512;
    const u16* Ab = attnb + (size_t)x * 64 * HDIM + koff;
    const u16* Bb = wob + (size_t)y * 64 * HDIM + koff;
    float* Cb = outp + (size_t)kc * 512 * 2048 + (size_t)x * 64 * 2048 + y * 64;
    gemm64_body(Ab, Bb, Cb, 2048, HDIM, 512, Ash, Bsh);
}

// sum 4 partial chunks -> out (float4 per thread), deterministic.
__global__ __launch_bounds__(256) void reduce4(
    const float* __restrict__ p, float* __restrict__ out, const size_t chunk)
{
    const size_t i = ((size_t)blockIdx.x * 256 + threadIdx.x) * 4;
    float4 a = *(const float4*)(p + i);
    float4 b = *(const float4*)(p + i + chunk);
    float4 c = *(const float4*)(p + i + 2 * chunk);
    float4 d = *(const float4*)(p + i + 3 * chunk);
    float4 r;
    r.x = (a.x + b.x) + (c.x + d.x);
    r.y = (a.y + b.y) + (c.y + d.y);
    r.z = (a.z + b.z) + (c.z + d.z);
    r.w = (a.w + b.w) + (c.w + d.w);
    *(float4*)(out + i) = r;
}

// ---------------- RMSNorm+RoPE on in-register values (half-wave) ----------
__device__ __forceinline__ void norm_rope_vals(
    float2 xa, float2 xb, const float* __restrict__ wgt,
    const float* __restrict__ cosT, const float* __restrict__ sinT,
    int pos, int j, float outScale, u16* __restrict__ dst)
{
    float ss = xa.x * xa.x + xa.y * xa.y + xb.x * xb.x + xb.y * xb.y;
#pragma unroll
    for (int m = 1; m < 32; m <<= 1) ss += __shfl_xor(ss, m);
    const float rr = rsqrtf(ss * (1.0f / 128.0f) + 1e-6f);
    float2 wa = *(const float2*)(wgt + 2 * j);
    float2 wb = *(const float2*)(wgt + 2 * j + 64);
    float2 ca = *(const float2*)(cosT + (size_t)pos * 128 + 2 * j);
    float2 sa = *(const float2*)(sinT + (size_t)pos * 128 + 2 * j);
    const float nax = xa.x * rr * wa.x, nay = xa.y * rr * wa.y;
    const float nbx = xb.x * rr * wb.x, nby = xb.y * rr * wb.y;
    const float lox = (nax * ca.x - nbx * sa.x) * outScale;
    const float loy = (nay * ca.y - nby * sa.y) * outScale;
    const float hix = (nbx * ca.x + nax * sa.x) * outScale;
    const float hiy = (nby * ca.y + nay * sa.y) * outScale;
    ((u32*)dst)[j]      = pack2(lox, loy);
    ((u32*)dst)[j + 32] = pack2(hix, hiy);
}

// ---------------- fused split-K reduce + RMSNorm/RoPE/cast ----------------
__global__ __launch_bounds__(256) void finalize_qkv(
    const float* __restrict__ qkvp, const float* __restrict__ qw,
    const float* __restrict__ kw, const float* __restrict__ cosT,
    const float* __restrict__ sinT,
    u16* __restrict__ Qb, u16* __restrict__ knb, u16* __restrict__ vnb)
{
    const int unit = blockIdx.x * 8 + (threadIdx.x >> 5);
    const int j = threadIdx.x & 31;
    const int slot = unit % 24, bq = unit / 24;
    const int b = bq >> 6, q = bq & 63;
    const int col0 = (slot < 16) ? slot * 128
                   : (slot < 20) ? 2048 + (slot - 16) * 128
                                 : 2560 + (slot - 20) * 128;
    const float* base = qkvp + (size_t)bq * 3072 + col0;

    float2 xa = {0.f, 0.f}, xb = {0.f, 0.f};
#pragma unroll
    for (int kc = 0; kc < 4; ++kc) {
        const float* p = base + (size_t)kc * 512 * 3072;
        float2 a = *(const float2*)(p + 2 * j);
        float2 c = *(const float2*)(p + 2 * j + 64);
        xa.x += a.x; xa.y += a.y; xb.x += c.x; xb.y += c.y;
    }

    if (slot < 16) {
        norm_rope_vals(xa, xb, qw, cosT, sinT, CTX + q, j, QSCALE,
                       Qb + ((size_t)((b * 16 + slot) * 64 + q)) * 128);
    } else if (slot < 20) {
        norm_rope_vals(xa, xb, kw, cosT, sinT, CTX + q, j, 1.0f,
                       knb + ((size_t)((b * 4 + (slot - 16)) * 64 + q)) * 128);
    } else {
        u16* dst = vnb + ((size_t)((b * 4 + (slot - 20)) * 64 + q)) * 128;
        ((u32*)dst)[j]      = pack2(xa.x, xa.y);
        ((u32*)dst)[j + 32] = pack2(xb.x, xb.y);
    }
}

// ---------------- ctx V^T build: LDS-staged transpose + vnb tail ----------
__global__ __launch_bounds__(256) void build_ctx_v(
    const float* __restrict__ ctxv, const u16* __restrict__ vnb,
    u16* __restrict__ VtG)
{
    __shared__ __align__(16) float Vt[64 * 130];
    const int bid = blockIdx.x;
    if (bid < 2048) {
        const int pt = bid & 63, kv = (bid >> 6) & 3, b = bid >> 8;
        const int p0 = pt * 64;
        const float* src = ctxv + ((size_t)(b * 4096 + p0) * 4 + kv) * 128;
#pragma unroll
        for (int it = 0; it < 8; ++it) {
            const int g = it * 256 + threadIdx.x;
            const int row = g >> 5, c4 = (g & 31) * 4;
            *(float4*)(&Vt[row * 130 + c4]) = *(const float4*)(src + (size_t)row * 512 + c4);
        }
        __syncthreads();
        const int d = threadIdx.x & 127, half = threadIdx.x >> 7;
        u16* dst = VtG + ((size_t)(b * 4 + kv) * 128 + d) * TTOT + p0 + half * 32;
#pragma unroll
        for (int q8 = 0; q8 < 4; ++q8) {
            s16x8 v;
#pragma unroll
            for (int je = 0; je < 8; ++je)
                v[je] = (short)f2bf(Vt[(half * 32 + q8 * 8 + je) * 130 + d]);
            *(s16x8*)(dst + q8 * 8) = v;
        }
    } else {
        const int idx = bid - 2048;   // b*4+kv
        const u16* src = vnb + (size_t)idx * 64 * 128;
        u16* dstb = VtG + (size_t)idx * 128 * TTOT + 4096;
        const int d = threadIdx.x & 127, qh = threadIdx.x >> 7;
        u16* dst = dstb + (size_t)d * TTOT + qh * 32;
#pragma unroll
        for (int q8 = 0; q8 < 4; ++q8) {
            s16x8 v;
#pragma unroll
            for (int je = 0; je < 8; ++je)
                v[je] = (short)src[(size_t)(qh * 32 + q8 * 8 + je) * 128 + d];
            *(s16x8*)(dst + q8 * 8) = v;
        }
    }
}

// ---------------- flash attention: 16 waves, fused K norm+rope ------------
// Round-14 counters: Occupancy 17%, VALU 25%, Mfma 12% -- latency-bound at
// 2 waves/SIMD (LDS 110.6KB forces 1 block/CU). Fix: 1024 threads = 16
// waves = 4 waves/SIMD. Wave w: head kv*4+(w>>2), q-quarter w&3 (16 rows)
// -> per-wave registers halve (fits the 128-VGPR cap of 1024-thr blocks).
// Staging: waves 0-7 stage+normalize K; waves 8-15 stage V + mask.
template <int S>
__global__ __launch_bounds__(1024) void attn_partial(
    const u16* __restrict__ Qb, const float* __restrict__ ctxk,
    const float* __restrict__ knw, const u16* __restrict__ cosb,
    const u16* __restrict__ sinb, const u16* __restrict__ knb,
    const u16* __restrict__ VtG, const u16* __restrict__ maskT,
    u16* __restrict__ Opart, float* __restrict__ lsum)
{
    __shared__ __align__(16) u16 Ksh[2][64 * 136];   // K [pos][d], padded
    __shared__ __align__(16) u16 Vsh[2][128 * 72];   // V^T [d][pos], padded
    __shared__ __align__(16) u16 Msh[2][64 * 72];    // maskT tile [pos][q]
    __shared__ __align__(16) u16 Psh[16][16 * 40];   // per-wave P chunk

    const int s = blockIdx.x, kv = blockIdx.y, b = blockIdx.z;
    const int tid = threadIdx.x, lane = tid & 63, w = tid >> 6;
    const int h = kv * 4 + (w >> 2);
    const int qq = w & 3, qbase = qq * 16;
    const int l15 = lane & 15, l4 = lane >> 4;
    const int t0 = (NTILES * s) / S, t1 = (NTILES * (s + 1)) / S;
    const bool isK = (tid < 512);            // wave-uniform staging role
    const int tid2 = tid & 511;

    // staging geometry
    const int krow = tid2 >> 3, kg8 = (tid2 & 7) * 8;   // K: 8 lanes/row
    const int vr = tid2 >> 2, vc = (tid2 & 3) * 16;     // V: 4 lanes/row
    const int mpos = tid2 >> 3, mq8 = (tid2 & 7) * 8;   // maskT row

    // K-norm weights (only meaningful for K-staging waves)
    const float4 w0 = *(const float4*)(knw + kg8);
    const float4 w1 = *(const float4*)(knw + kg8 + 4);
    const float4 w2 = *(const float4*)(knw + kg8 + 64);
    const float4 w3 = *(const float4*)(knw + kg8 + 68);

    bf16x8 aq[4];
    {
        const u16* qb = Qb + ((size_t)((b * 16 + h) * 64 + qbase)) * 128;
#pragma unroll
        for (int ks = 0; ks < 4; ++ks)
            aq[ks] = *(const bf16x8*)(qb + l15 * 128 + ks * 32 + l4 * 8);
    }

    bf16x8 bones;   // col-0 ones -> P row sums via MFMA
    {
        __bf16 e = (l15 == 0) ? (__bf16)1.0f : (__bf16)0.0f;
#pragma unroll
        for (int i = 0; i < 8; ++i) bones[i] = e;
    }

    f32x4 o[8], ol;
    ol = (f32x4){0.f, 0.f, 0.f, 0.f};
#pragma unroll
    for (int nt = 0; nt < 8; ++nt) o[nt] = (f32x4){0.f, 0.f, 0.f, 0.f};

    const u16* Kn    = knb + (size_t)(b * 4 + kv) * 64 * 128;
    const u16* Vbase = VtG + (size_t)(b * 4 + kv) * 128 * TTOT;
    const u16* mrow  = maskT + (size_t)b * TTOT * 64;
    u16* P = Psh[w];

    float4 rx0, rx1, rx2, rx3;          // raw K f32 (tiles 0..63)
    s16x8 rcs, rsn;                     // bf16 cos/sin slice
    s16x8 rkn0, rkn1;                   // knb bf16 (tile 64)
    s16x8 rv0, rv1, rm;
    int tin = -1;

    auto ld = [&](int t) {
        const int p = t * 64;
        if (isK) {
            if (t < 64) {
                const float* kp_ = ctxk + (((size_t)(b * 4096 + p + krow)) * 4 + kv) * 128 + kg8;
                rx0 = *(const float4*)kp_;        rx1 = *(const float4*)(kp_ + 4);
                rx2 = *(const float4*)(kp_ + 64); rx3 = *(const float4*)(kp_ + 68);
                rcs = *(const s16x8*)(cosb + (size_t)(p + krow) * 64 + kg8);
                rsn = *(const s16x8*)(sinb + (size_t)(p + krow) * 64 + kg8);
            } else {
                const u16* kp2 = Kn + (size_t)krow * 128 + kg8;
                rkn0 = *(const s16x8*)kp2;
                rkn1 = *(const s16x8*)(kp2 + 64);
            }
        } else {
            rv0 = *(const s16x8*)(Vbase + (size_t)vr * TTOT + p + vc);
            rv1 = *(const s16x8*)(Vbase + (size_t)vr * TTOT + p + vc + 8);
            rm  = *(const s16x8*)(mrow + (size_t)(p + mpos) * 64 + mq8);
        }
        tin = t;
        __builtin_amdgcn_sched_barrier(0);   // pin load issue here
    };
    auto st = [&](int buf) {
        if (isK) {
            if (tin < 64) {
                float ss = rx0.x*rx0.x + rx0.y*rx0.y + rx0.z*rx0.z + rx0.w*rx0.w
                         + rx1.x*rx1.x + rx1.y*rx1.y + rx1.z*rx1.z + rx1.w*rx1.w
                         + rx2.x*rx2.x + rx2.y*rx2.y + rx2.z*rx2.z + rx2.w*rx2.w
                         + rx3.x*rx3.x + rx3.y*rx3.y + rx3.z*rx3.z + rx3.w*rx3.w;
                ss += __shfl_xor(ss, 1);
                ss += __shfl_xor(ss, 2);
                ss += __shfl_xor(ss, 4);
                const float rr = rsqrtf(ss * (1.0f / 128.0f) + 1e-6f);
                s16x8 klo, khi;
#define KROPE(i, xl, xh, wl, wh)                                     \
                {                                                    \
                    const float nlo = xl * rr * wl, nhi = xh * rr * wh; \
                    const float c = bf2f((u16)rcs[i]), sn = bf2f((u16)rsn[i]); \
                    klo[i] = (short)f2bf(nlo * c - nhi * sn);        \
                    khi[i] = (short)f2bf(nhi * c + nlo * sn);        \
                }
                KROPE(0, rx0.x, rx2.x, w0.x, w2.x)
                KROPE(1, rx0.y, rx2.y, w0.y, w2.y)
                KROPE(2, rx0.z, rx2.z, w0.z, w2.z)
                KROPE(3, rx0.w, rx2.w, w0.w, w2.w)
                KROPE(4, rx1.x, rx3.x, w1.x, w3.x)
                KROPE(5, rx1.y, rx3.y, w1.y, w3.y)
                KROPE(6, rx1.z, rx3.z, w1.z, w3.z)
                KROPE(7, rx1.w, rx3.w, w1.w, w3.w)
#undef KROPE
                *(s16x8*)(Ksh[buf] + krow * 136 + kg8)      = klo;
                *(s16x8*)(Ksh[buf] + krow * 136 + 64 + kg8) = khi;
            } else {
                *(s16x8*)(Ksh[buf] + krow * 136 + kg8)      = rkn0;
                *(s16x8*)(Ksh[buf] + krow * 136 + 64 + kg8) = rkn1;
            }
        } else {
            *(s16x8*)(Vsh[buf] + vr * 72 + vc)     = rv0;
            *(s16x8*)(Vsh[buf] + vr * 72 + vc + 8) = rv1;
            *(s16x8*)(Msh[buf] + mpos * 72 + mq8)  = rm;
        }
    };

    // prologue
    ld(t0);
    st(0);
    __syncthreads();
    if (t0 + 1 < t1) ld(t0 + 1);

    int cur = 0;
    for (int t = t0; t < t1; ++t) {
        // ---- compute tile t from buf[cur] ----
        f32x4 sc[4];
#pragma unroll
        for (int nt = 0; nt < 4; ++nt) sc[nt] = (f32x4){0.f, 0.f, 0.f, 0.f};
        __builtin_amdgcn_s_setprio(1);
#pragma unroll
        for (int nt = 0; nt < 4; ++nt) {
#pragma unroll
            for (int ks = 0; ks < 4; ++ks) {
                bf16x8 bk = *(const bf16x8*)(Ksh[cur] + (nt * 16 + l15) * 136 + ks * 32 + l4 * 8);
                sc[nt] = mfma16(aq[ks], bk, sc[nt]);
            }
        }
        __builtin_amdgcn_s_setprio(0);

        // fixed-max softmax: p = exp2(sc + msh); msh pre-folded bf16 [pos][q]
#pragma unroll
        for (int nt = 0; nt < 4; ++nt) {
            u16x4 m4 = *(const u16x4*)(Msh[cur] + (nt * 16 + l15) * 72 + qbase + l4 * 4);
#pragma unroll
            for (int r = 0; r < 4; ++r)
                sc[nt][r] = exp2f(sc[nt][r] + bf2f(m4[r]));
        }

        // O += P V ; l += P 1
#pragma unroll
        for (int ks = 0; ks < 2; ++ks) {
#pragma unroll
            for (int r = 0; r < 4; ++r) {
                P[(l4 * 4 + r) * 40 + l15]      = f2bf(sc[ks * 2 + 0][r]);
                P[(l4 * 4 + r) * 40 + 16 + l15] = f2bf(sc[ks * 2 + 1][r]);
            }
            bf16x8 ap = *(const bf16x8*)(P + l15 * 40 + l4 * 8);
            __builtin_amdgcn_s_setprio(1);
#pragma unroll
            for (int nt = 0; nt < 8; ++nt) {
                bf16x8 bv = *(const bf16x8*)(Vsh[cur] + (nt * 16 + l15) * 72 + ks * 32 + l4 * 8);
                o[nt] = mfma16(ap, bv, o[nt]);
            }
            ol = mfma16(ap, bones, ol);
            __builtin_amdgcn_s_setprio(0);
        }

        // ---- stage tile t+1 into buf[cur^1]; prefetch t+2 ----
        if (t + 1 < t1) st(cur ^ 1);
        __syncthreads();
        if (t + 2 < t1) ld(t + 2);
        cur ^= 1;
    }

    // coalesced epilogue: Opart chunk per (b,h,s): wave qq owns 2048 u16
    {
        u16* ob = Opart + ((size_t)((b * 16 + h) * S + s)) * 8192 + qq * 2048;
#pragma unroll
        for (int nt = 0; nt < 8; ++nt) {
            u16x4 v;
#pragma unroll
            for (int r = 0; r < 4; ++r) v[r] = f2bf(o[nt][r]);
            *(u16x4*)(ob + nt * 256 + lane * 4) = v;
        }
        if (l15 == 0) {
#pragma unroll
            for (int r = 0; r < 4; ++r) {
                const int q = qbase + l4 * 4 + r;
                lsum[((size_t)((b * 16 + h) * 64 + q)) * S + s] = ol[r];
            }
        }
    }
}

// ---------------- merge splits -> attn (B,K,NH*HD) bf16 -------------------
template <int S>
__global__ __launch_bounds__(256) void merge_kernel(
    const u16* __restrict__ Opart, const float* __restrict__ lsum, u16* __restrict__ attnb)
{
    const int wid = blockIdx.x * 4 + (threadIdx.x >> 6);   // (b*16+h)*2 + qh
    const int lane = threadIdx.x & 63;
    const int l15 = lane & 15, l4 = lane >> 4;
    const int qh = wid & 1, bh = wid >> 1;
    const int h = bh & 15, b = bh >> 4;

    float L = 0.f;
    {
        const float* lr = lsum + ((size_t)bh * 64 + qh * 32 + (lane & 31)) * S;
#pragma unroll
        for (int s2 = 0; s2 < S; ++s2) L += lr[s2];
    }
    const float invL = 1.0f / L;

    float acc[2][8][4];
#pragma unroll
    for (int mt = 0; mt < 2; ++mt)
#pragma unroll
        for (int nt = 0; nt < 8; ++nt)
#pragma unroll
            for (int r = 0; r < 4; ++r) acc[mt][nt][r] = 0.f;

    for (int s2 = 0; s2 < S; ++s2) {
        const u16* ob = Opart + ((size_t)(bh * S + s2)) * 8192;
#pragma unroll
        for (int mt = 0; mt < 2; ++mt)
#pragma unroll
            for (int nt = 0; nt < 8; ++nt) {
                u16x4 v = *(const u16x4*)(ob + (((qh * 2 + mt) * 8 + nt) * 64 + lane) * 4);
#pragma unroll
                for (int r = 0; r < 4; ++r) acc[mt][nt][r] += bf2f(v[r]);
            }
    }

#pragma unroll
    for (int mt = 0; mt < 2; ++mt)
#pragma unroll
        for (int r = 0; r < 4; ++r) {
            const float wl = __shfl(invL, mt * 16 + l4 * 4 + r);
            const int q = qh * 32 + mt * 16 + l4 * 4 + r;
            u16* dst = attnb + (size_t)(b * 64 + q) * 2048 + h * 128;
#pragma unroll
            for (int nt = 0; nt < 8; ++nt)
                dst[nt * 16 + l15] = f2bf(acc[mt][nt][r] * wl);
        }
}

// ---------------- launch ----------------
extern "C" void kernel_launch(void* const* d_in, const int* in_sizes, int n_in,
                              void* d_out, int out_size, void* d_ws, size_t ws_size,
                              hipStream_t stream)
{
    (void)in_sizes; (void)n_in; (void)out_size; (void)ws_size;
    const float* hs   = (const float*)d_in[0];
    const float* ctxk = (const float*)d_in[1];
    const float* ctxv = (const float*)d_in[2];
    const float* mask = (const float*)d_in[3];
    const float* cosT = (const float*)d_in[4];
    const float* sinT = (const float*)d_in[5];
    const float* wq   = (const float*)d_in[6];
    const float* wk   = (const float*)d_in[7];
    const float* wv   = (const float*)d_in[8];
    const float* wo   = (const float*)d_in[9];
    const float* qnw  = (const float*)d_in[10];
    const float* knw  = (const float*)d_in[11];

    const int S = 8;

    char* ws = (char*)d_ws;
    size_t off = 0;
    auto carve = [&](size_t bytes) -> void* {
        void* p = ws + off;
        off += (bytes + 255) & ~(size_t)255;
        return p;
    };
    u16*   Qb    = (u16*)carve((size_t)BB * NH * 64 * 128 * 2);         // 2.1 MB
    u16*   VtG   = (u16*)carve((size_t)BB * NKV * TTOT * 128 * 2);      // 34.1 MB
    u16*   Opart = (u16*)carve((size_t)BB * NH * S * 8192 * 2);         // 16.8 MB
    float* lsumb = (float*)carve((size_t)BB * NH * 64 * S * 4);         // 0.26 MB
    u16*   attnb = (u16*)carve((size_t)512 * 2048 * 2);                 // 2.1 MB
    u16*   wob   = (u16*)carve((size_t)2048 * 2048 * 2);                // 8.4 MB
    u16*   wqkvb = (u16*)carve((size_t)3072 * 2048 * 2);                // 12.6 MB
    u16*   knb   = (u16*)carve((size_t)BB * NKV * 64 * 128 * 2);        // 0.52 MB
    u16*   vnb   = (u16*)carve((size_t)BB * NKV * 64 * 128 * 2);        // 0.52 MB
    u16*   maskT = (u16*)carve((size_t)BB * TTOT * 64 * 2);             // 4.3 MB
    u16*   cosb  = (u16*)carve((size_t)TTOT * 64 * 2);                  // 0.53 MB
    u16*   sinb  = (u16*)carve((size_t)TTOT * 64 * 2);                  // 0.53 MB
    // ~82.8 MB. Time-multiplexed aliases (stream-ordered liveness):
    float* qkvp = (float*)VtG;    // qkv split-K partials; dead before build_ctx_v
    u16*   hsb  = (u16*)Opart;    // bf16 hs; dead before attn_partial
    float* outp = (float*)Opart;  // out partials; Opart dead after merge

    // 1) cast weights/activations + bf16 cos/sin half-tables; fold mask
    cast_all<<<5892, 256, 0, stream>>>(wq, wk, wv, wo, hs, cosT, sinT,
                                       wqkvb, wob, hsb, cosb, sinb);
    prep_mask<<<520, 256, 0, stream>>>(mask, maskT);
    // 2) QKV projection (bf16, split-K x4, XCD swizzle)
    gemm_qkv_sk<<<1536, 256, 0, stream>>>(hsb, wqkvb, qkvp);
    // 3) fused reduce + RMSNorm/RoPE/cast -> Qb, k-noise, v-noise
    finalize_qkv<<<1536, 256, 0, stream>>>(qkvp, qnw, knw, cosT, sinT, Qb, knb, vnb);
    // 4) ctx V^T (LDS-staged transpose); K build is FUSED into attn
    build_ctx_v<<<2080, 256, 0, stream>>>(ctxv, vnb, VtG);
    // 5) flash attention (16 waves, fused K norm+rope) + merge
    attn_partial<8><<<dim3(8, NKV, BB), 1024, 0, stream>>>(
        Qb, ctxk, knw, cosb, sinb, knb, VtG, maskT, Opart, lsumb);
    merge_kernel<8><<<64, 256, 0, stream>>>(Opart, lsumb, attnb);
    // 6) output projection (bf16, split-K x4, XCD swizzle) -> reduce
    gemm_out_sk<<<1024, 256, 0, stream>>>(attnb, wob, outp);
    reduce4<<<1024, 256, 0, stream>>>(outp, (float*)d_out, (size_t)512 * 2048);
}

// Round 16
// 170.531 us; speedup vs baseline: 1.0954x; 1.0954x over previous
//
#include <hip/hip_runtime.h>

// ---------------- problem constants ----------------
#define BB   8
#define KQ   64
#define HDIM 2048
#define NH   16
#define NKV  4
#define HD   128
#define CTX  4096
#define TTOT 4160      // CTX + KQ
#define NTILES 65      // TTOT / 64
#define LOG2E 1.4426950408889634f
#define SCALE 0.08838834764831845f  // 1/sqrt(128)
#define QSCALE (SCALE * LOG2E)      // folded into Q; exp2-domain softmax
// |q.k| <= 128 after RMS-norm => |sc| <= 128*QSCALE = 16.33. Fixed softmax max.
#define MFIX 16.34f

typedef unsigned short u16;
typedef unsigned int   u32;
typedef __attribute__((ext_vector_type(8))) short  s16x8;   // bf16 storage
typedef __attribute__((ext_vector_type(4))) unsigned short u16x4;
typedef __attribute__((ext_vector_type(4))) float  f32x4;
typedef __bf16 bf16x8 __attribute__((ext_vector_type(8)));  // MFMA operand

__device__ __forceinline__ u16 f2bf(float f) {              // HW RNE cvt
    union { __bf16 h; u16 u; } v; v.h = (__bf16)f; return v.u;
}
__device__ __forceinline__ float bf2f(u16 u) {
    union { float f; u32 u; } v; v.u = ((u32)u) << 16;
    return v.f;
}
__device__ __forceinline__ u32 pack2(float a, float b) {
    return (u32)f2bf(a) | ((u32)f2bf(b) << 16);
}
__device__ __forceinline__ f32x4 mfma16(bf16x8 a, bf16x8 b, f32x4 c) {
    return __builtin_amdgcn_mfma_f32_16x16x32_bf16(a, b, c, 0, 0, 0);
}

// ---------------- fused f32 -> bf16 cast of 5 tensors + cos/sin tables ----
__global__ __launch_bounds__(256) void cast_all(
    const float* __restrict__ wq, const float* __restrict__ wk,
    const float* __restrict__ wv, const float* __restrict__ wo,
    const float* __restrict__ hs, const float* __restrict__ cosT,
    const float* __restrict__ sinT,
    u16* __restrict__ wqkvb, u16* __restrict__ wob, u16* __restrict__ hsb,
    u16* __restrict__ cosb, u16* __restrict__ sinb)
{
    const int i = blockIdx.x * 256 + threadIdx.x;
    const float* src; u16* dst;
    if (i < 524288)        { src = wq + (size_t)i * 8;             dst = wqkvb + (size_t)i * 8; }
    else if (i < 655360)   { src = wk + (size_t)(i - 524288) * 8;  dst = wqkvb + (size_t)i * 8; }
    else if (i < 786432)   { src = wv + (size_t)(i - 655360) * 8;  dst = wqkvb + (size_t)i * 8; }
    else if (i < 1310720)  { src = wo + (size_t)(i - 786432) * 8;  dst = wob + (size_t)(i - 786432) * 8; }
    else if (i < 1441792)  { src = hs + (size_t)(i - 1310720) * 8; dst = hsb + (size_t)(i - 1310720) * 8; }
    else if (i < 1475072)  { const int l = (i - 1441792) * 8;
                             src = cosT + (size_t)(l >> 6) * 128 + (l & 63); dst = cosb + l; }
    else                   { const int l = (i - 1475072) * 8;
                             src = sinT + (size_t)(l >> 6) * 128 + (l & 63); dst = sinb + l; }
    float4 a = *(const float4*)src;
    float4 b = *(const float4*)(src + 4);
    s16x8 v;
    v[0]=(short)f2bf(a.x); v[1]=(short)f2bf(a.y); v[2]=(short)f2bf(a.z); v[3]=(short)f2bf(a.w);
    v[4]=(short)f2bf(b.x); v[5]=(short)f2bf(b.y); v[6]=(short)f2bf(b.z); v[7]=(short)f2bf(b.w);
    *(s16x8*)dst = v;
}

// ---------------- mask pre-transpose: maskT[b][pos][q] bf16 ---------------
__global__ __launch_bounds__(256) void prep_mask(
    const float* __restrict__ mask, u16* __restrict__ maskT)
{
    __shared__ float T[64 * 65];
    const int pt = blockIdx.x % 65, b = blockIdx.x / 65;
    const int p0 = pt * 64;
    {
        const int q = threadIdx.x >> 2, pg = (threadIdx.x & 3) * 16;
        const float* src = mask + ((size_t)b * 64 + q) * TTOT + p0 + pg;
#pragma unroll
        for (int v4 = 0; v4 < 4; ++v4) {
            float4 v = *(const float4*)(src + v4 * 4);
            T[q * 65 + pg + v4 * 4 + 0] = fmaf(v.x, LOG2E, -MFIX);
            T[q * 65 + pg + v4 * 4 + 1] = fmaf(v.y, LOG2E, -MFIX);
            T[q * 65 + pg + v4 * 4 + 2] = fmaf(v.z, LOG2E, -MFIX);
            T[q * 65 + pg + v4 * 4 + 3] = fmaf(v.w, LOG2E, -MFIX);
        }
    }
    __syncthreads();
    {
        const int pos = threadIdx.x >> 2, qg = (threadIdx.x & 3) * 16;
        u16* dst = maskT + ((size_t)b * TTOT + p0 + pos) * 64 + qg;
#pragma unroll
        for (int h8 = 0; h8 < 2; ++h8) {
            s16x8 v;
#pragma unroll
            for (int je = 0; je < 8; ++je)
                v[je] = (short)f2bf(T[(qg + h8 * 8 + je) * 65 + pos]);
            *(s16x8*)(dst + h8 * 8) = v;
        }
    }
}

// ---------------- 64x64-tile GEMM core, bf16 inputs (padded LDS) ----------
__device__ __forceinline__ void gemm64_body(
    const u16* __restrict__ Ab, const u16* __restrict__ Bb,
    float* __restrict__ Cb, const int ldc, const int ldk, const int Klen,
    u16* Ash, u16* Bsh)
{
    const int tid = threadIdx.x, lane = tid & 63;
    const int w = tid >> 6, wm = w >> 1, wn = w & 1;
    const int l15 = lane & 15, l4 = lane >> 4;
    const int srow = tid >> 2, scol = (tid & 3) * 16;

    f32x4 acc[2][2];
#pragma unroll
    for (int i = 0; i < 2; ++i)
#pragma unroll
        for (int j = 0; j < 2; ++j) acc[i][j] = (f32x4){0.f, 0.f, 0.f, 0.f};

    const u16* ap = Ab + (size_t)srow * ldk + scol;
    const u16* bp = Bb + (size_t)srow * ldk + scol;
    s16x8 ra0 = *(const s16x8*)ap, ra1 = *(const s16x8*)(ap + 8);
    s16x8 rb0 = *(const s16x8*)bp, rb1 = *(const s16x8*)(bp + 8);
    __builtin_amdgcn_sched_barrier(0);

    for (int k0 = 0; k0 < Klen; k0 += 64) {
        __syncthreads();
        *(s16x8*)(Ash + srow * 72 + scol)     = ra0;
        *(s16x8*)(Ash + srow * 72 + scol + 8) = ra1;
        *(s16x8*)(Bsh + srow * 72 + scol)     = rb0;
        *(s16x8*)(Bsh + srow * 72 + scol + 8) = rb1;
        __syncthreads();
        if (k0 + 64 < Klen) {
            const u16* ap2 = ap + k0 + 64;
            const u16* bp2 = bp + k0 + 64;
            ra0 = *(const s16x8*)ap2; ra1 = *(const s16x8*)(ap2 + 8);
            rb0 = *(const s16x8*)bp2; rb1 = *(const s16x8*)(bp2 + 8);
            __builtin_amdgcn_sched_barrier(0);
        }
#pragma unroll
        for (int ks = 0; ks < 2; ++ks) {
            bf16x8 am[2], bb[2];
#pragma unroll
            for (int i = 0; i < 2; ++i) {
                am[i] = *(const bf16x8*)(Ash + (wm * 32 + i * 16 + l15) * 72 + ks * 32 + l4 * 8);
                bb[i] = *(const bf16x8*)(Bsh + (wn * 32 + i * 16 + l15) * 72 + ks * 32 + l4 * 8);
            }
#pragma unroll
            for (int i = 0; i < 2; ++i)
#pragma unroll
                for (int j = 0; j < 2; ++j)
                    acc[i][j] = mfma16(am[i], bb[j], acc[i][j]);
        }
    }

    float* Cw = Cb + (size_t)(wm * 32) * ldc + wn * 32;
#pragma unroll
    for (int i = 0; i < 2; ++i)
#pragma unroll
        for (int j = 0; j < 2; ++j)
#pragma unroll
            for (int r = 0; r < 4; ++r)
                Cw[(size_t)(i * 16 + l4 * 4 + r) * ldc + j * 16 + l15] = acc[i][j][r];
}

// QKV projection, split-K x4, XCD-chunked swizzle. 1D grid 1536.
__global__ __launch_bounds__(256) void gemm_qkv_sk(
    const u16* __restrict__ hsb, const u16* __restrict__ wqkvb,
    float* __restrict__ qkvp)
{
    __shared__ __align__(16) u16 Ash[64 * 72];
    __shared__ __align__(16) u16 Bsh[64 * 72];
    const int wid = (blockIdx.x & 7) * 192 + (blockIdx.x >> 3);
    const int y = wid >> 5, rem = wid & 31, kc = rem >> 3, x = rem & 7;
    const int koff = kc * 512;
    const u16* Ab = hsb + (size_t)x * 64 * HDIM + koff;
    const u16* Bb = wqkvb + (size_t)y * 64 * HDIM + koff;
    float* Cb = qkvp + (size_t)kc * 512 * 3072 + (size_t)x * 64 * 3072 + y * 64;
    gemm64_body(Ab, Bb, Cb, 3072, HDIM, 512, Ash, Bsh);
}

// Output projection, split-K x4, XCD-chunked swizzle. 1D grid 1024.
__global__ __launch_bounds__(256) void gemm_out_sk(
    const u16* __restrict__ attnb, const u16* __restrict__ wob,
    float* __restrict__ outp)
{
    __shared__ __align__(16) u16 Ash[64 * 72];
    __shared__ __align__(16) u16 Bsh[64 * 72];
    const int wid = (blockIdx.x & 7) * 128 + (blockIdx.x >> 3);
    const int y = wid >> 5, rem = wid & 31, kc = rem >> 3, x = rem & 7;
    const int koff = kc * 512;
    const u16* Ab = attnb + (size_t)x * 64 * HDIM + koff;
    const u16* Bb = wob + (size_t)y * 64 * HDIM + koff;
    float* Cb = outp + (size_t)kc * 512 * 2048 + (size_t)x * 64 * 2048 + y * 64;
    gemm64_body(Ab, Bb, Cb, 2048, HDIM, 512, Ash, Bsh);
}

// sum 4 partial chunks -> out (float4 per thread), deterministic.
__global__ __launch_bounds__(256) void reduce4(
    const float* __restrict__ p, float* __restrict__ out, const size_t chunk)
{
    const size_t i = ((size_t)blockIdx.x * 256 + threadIdx.x) * 4;
    float4 a = *(const float4*)(p + i);
    float4 b = *(const float4*)(p + i + chunk);
    float4 c = *(const float4*)(p + i + 2 * chunk);
    float4 d = *(const float4*)(p + i + 3 * chunk);
    float4 r;
    r.x = (a.x + b.x) + (c.x + d.x);
    r.y = (a.y + b.y) + (c.y + d.y);
    r.z = (a.z + b.z) + (c.z + d.z);
    r.w = (a.w + b.w) + (c.w + d.w);
    *(float4*)(out + i) = r;
}

// ---------------- RMSNorm+RoPE on in-register values (half-wave) ----------
__device__ __forceinline__ void norm_rope_vals(
    float2 xa, float2 xb, const float* __restrict__ wgt,
    const float* __restrict__ cosT, const float* __restrict__ sinT,
    int pos, int j, float outScale, u16* __restrict__ dst)
{
    float ss = xa.x * xa.x + xa.y * xa.y + xb.x * xb.x + xb.y * xb.y;
#pragma unroll
    for (int m = 1; m < 32; m <<= 1) ss += __shfl_xor(ss, m);
    const float rr = rsqrtf(ss * (1.0f / 128.0f) + 1e-6f);
    float2 wa = *(const float2*)(wgt + 2 * j);
    float2 wb = *(const float2*)(wgt + 2 * j + 64);
    float2 ca = *(const float2*)(cosT + (size_t)pos * 128 + 2 * j);
    float2 sa = *(const float2*)(sinT + (size_t)pos * 128 + 2 * j);
    const float nax = xa.x * rr * wa.x, nay = xa.y * rr * wa.y;
    const float nbx = xb.x * rr * wb.x, nby = xb.y * rr * wb.y;
    const float lox = (nax * ca.x - nbx * sa.x) * outScale;
    const float loy = (nay * ca.y - nby * sa.y) * outScale;
    const float hix = (nbx * ca.x + nax * sa.x) * outScale;
    const float hiy = (nby * ca.y + nay * sa.y) * outScale;
    ((u32*)dst)[j]      = pack2(lox, loy);
    ((u32*)dst)[j + 32] = pack2(hix, hiy);
}

// ---------------- fused split-K reduce + RMSNorm/RoPE/cast ----------------
__global__ __launch_bounds__(256) void finalize_qkv(
    const float* __restrict__ qkvp, const float* __restrict__ qw,
    const float* __restrict__ kw, const float* __restrict__ cosT,
    const float* __restrict__ sinT,
    u16* __restrict__ Qb, u16* __restrict__ knb, u16* __restrict__ vnb)
{
    const int unit = blockIdx.x * 8 + (threadIdx.x >> 5);
    const int j = threadIdx.x & 31;
    const int slot = unit % 24, bq = unit / 24;
    const int b = bq >> 6, q = bq & 63;
    const int col0 = (slot < 16) ? slot * 128
                   : (slot < 20) ? 2048 + (slot - 16) * 128
                                 : 2560 + (slot - 20) * 128;
    const float* base = qkvp + (size_t)bq * 3072 + col0;

    float2 xa = {0.f, 0.f}, xb = {0.f, 0.f};
#pragma unroll
    for (int kc = 0; kc < 4; ++kc) {
        const float* p = base + (size_t)kc * 512 * 3072;
        float2 a = *(const float2*)(p + 2 * j);
        float2 c = *(const float2*)(p + 2 * j + 64);
        xa.x += a.x; xa.y += a.y; xb.x += c.x; xb.y += c.y;
    }

    if (slot < 16) {
        norm_rope_vals(xa, xb, qw, cosT, sinT, CTX + q, j, QSCALE,
                       Qb + ((size_t)((b * 16 + slot) * 64 + q)) * 128);
    } else if (slot < 20) {
        norm_rope_vals(xa, xb, kw, cosT, sinT, CTX + q, j, 1.0f,
                       knb + ((size_t)((b * 4 + (slot - 16)) * 64 + q)) * 128);
    } else {
        u16* dst = vnb + ((size_t)((b * 4 + (slot - 20)) * 64 + q)) * 128;
        ((u32*)dst)[j]      = pack2(xa.x, xa.y);
        ((u32*)dst)[j + 32] = pack2(xb.x, xb.y);
    }
}

// ---------------- ctx V^T build: LDS-staged transpose + vnb tail ----------
__global__ __launch_bounds__(256) void build_ctx_v(
    const float* __restrict__ ctxv, const u16* __restrict__ vnb,
    u16* __restrict__ VtG)
{
    __shared__ __align__(16) float Vt[64 * 130];
    const int bid = blockIdx.x;
    if (bid < 2048) {
        const int pt = bid & 63, kv = (bid >> 6) & 3, b = bid >> 8;
        const int p0 = pt * 64;
        const float* src = ctxv + ((size_t)(b * 4096 + p0) * 4 + kv) * 128;
#pragma unroll
        for (int it = 0; it < 8; ++it) {
            const int g = it * 256 + threadIdx.x;
            const int row = g >> 5, c4 = (g & 31) * 4;
            *(float4*)(&Vt[row * 130 + c4]) = *(const float4*)(src + (size_t)row * 512 + c4);
        }
        __syncthreads();
        const int d = threadIdx.x & 127, half = threadIdx.x >> 7;
        u16* dst = VtG + ((size_t)(b * 4 + kv) * 128 + d) * TTOT + p0 + half * 32;
#pragma unroll
        for (int q8 = 0; q8 < 4; ++q8) {
            s16x8 v;
#pragma unroll
            for (int je = 0; je < 8; ++je)
                v[je] = (short)f2bf(Vt[(half * 32 + q8 * 8 + je) * 130 + d]);
            *(s16x8*)(dst + q8 * 8) = v;
        }
    } else {
        const int idx = bid - 2048;   // b*4+kv
        const u16* src = vnb + (size_t)idx * 64 * 128;
        u16* dstb = VtG + (size_t)idx * 128 * TTOT + 4096;
        const int d = threadIdx.x & 127, qh = threadIdx.x >> 7;
        u16* dst = dstb + (size_t)d * TTOT + qh * 32;
#pragma unroll
        for (int q8 = 0; q8 < 4; ++q8) {
            s16x8 v;
#pragma unroll
            for (int je = 0; je < 8; ++je)
                v[je] = (short)src[(size_t)(qh * 32 + q8 * 8 + je) * 128 + d];
            *(s16x8*)(dst + q8 * 8) = v;
        }
    }
}

// ---------------- flash attention: 512 thr, single-buf K/M, 2 blk/CU ------
// Round-15 lesson: 1024-thr block -> 64-VGPR cap -> spills (WRITE 181MB).
// Occupancy must come from LDS instead: K is read only in the QK phase and
// M only in softmax, both before a mid-tile barrier -> single-buffer both
// and overwrite during PV. LDS 79.4KB (<80) + S=16 (512 blocks) -> 2
// blocks/CU = 4 waves/SIMD at VGPR<=128. Pads 132/68/36 are also
// conflict-free for the b128 read strides (136 was 8-way).
template <int S>
__global__ __launch_bounds__(512, 2) void attn_partial(
    const u16* __restrict__ Qb, const float* __restrict__ ctxk,
    const float* __restrict__ knw, const u16* __restrict__ cosb,
    const u16* __restrict__ sinb, const u16* __restrict__ knb,
    const u16* __restrict__ VtG, const u16* __restrict__ maskT,
    u16* __restrict__ Opart, float* __restrict__ lsum)
{
    __shared__ __align__(16) u16 Ksh[64 * 132];      // K [pos][d], single buf
    __shared__ __align__(16) u16 Vsh[2][128 * 68];   // V^T [d][pos], dbuf
    __shared__ __align__(16) u16 Msh[64 * 72];       // maskT tile, single buf
    __shared__ __align__(16) u16 Psh[8][32 * 36];    // per-wave P chunk

    const int s = blockIdx.x, kv = blockIdx.y, b = blockIdx.z;
    const int tid = threadIdx.x, lane = tid & 63, w = tid >> 6;
    const int h = kv * 4 + (w >> 1);
    const int qh = w & 1, qbase = qh * 32;
    const int l15 = lane & 15, l4 = lane >> 4;
    const int t0 = (NTILES * s) / S, t1 = (NTILES * (s + 1)) / S;

    const int krow = tid >> 3, kg8 = (tid & 7) * 8;
    const int vr = tid >> 3, vc8 = (tid & 7) * 8;
    const int mpos = tid >> 3, mq8 = (tid & 7) * 8;

    const float4 w0 = *(const float4*)(knw + kg8);
    const float4 w1 = *(const float4*)(knw + kg8 + 4);
    const float4 w2 = *(const float4*)(knw + kg8 + 64);
    const float4 w3 = *(const float4*)(knw + kg8 + 68);

    bf16x8 aq[2][4];
    {
        const u16* qb = Qb + ((size_t)((b * 16 + h) * 64 + qbase)) * 128;
#pragma unroll
        for (int mt = 0; mt < 2; ++mt)
#pragma unroll
            for (int ks = 0; ks < 4; ++ks)
                aq[mt][ks] = *(const bf16x8*)(qb + (mt * 16 + l15) * 128 + ks * 32 + l4 * 8);
    }

    bf16x8 bones;   // col-0 ones -> P row sums via MFMA
    {
        __bf16 e = (l15 == 0) ? (__bf16)1.0f : (__bf16)0.0f;
#pragma unroll
        for (int i = 0; i < 8; ++i) bones[i] = e;
    }

    f32x4 o[2][8], ol[2];
#pragma unroll
    for (int mt = 0; mt < 2; ++mt) {
        ol[mt] = (f32x4){0.f, 0.f, 0.f, 0.f};
#pragma unroll
        for (int nt = 0; nt < 8; ++nt) o[mt][nt] = (f32x4){0.f, 0.f, 0.f, 0.f};
    }

    const u16* Kn    = knb + (size_t)(b * 4 + kv) * 64 * 128;
    const u16* Vbase = VtG + (size_t)(b * 4 + kv) * 128 * TTOT;
    const u16* mrow  = maskT + (size_t)b * TTOT * 64;
    u16* P = Psh[w];

    float4 rx0, rx1, rx2, rx3;          // raw K f32 (tiles 0..63)
    s16x8 rcs, rsn;                     // bf16 cos/sin slice
    s16x8 rkn0, rkn1;                   // knb bf16 (tile 64)
    s16x8 rv0, rv1, rm;
    int tin = -1;

    auto ld = [&](int t) {
        const int p = t * 64;
        if (t < 64) {
            const float* kp_ = ctxk + (((size_t)(b * 4096 + p + krow)) * 4 + kv) * 128 + kg8;
            rx0 = *(const float4*)kp_;        rx1 = *(const float4*)(kp_ + 4);
            rx2 = *(const float4*)(kp_ + 64); rx3 = *(const float4*)(kp_ + 68);
            rcs = *(const s16x8*)(cosb + (size_t)(p + krow) * 64 + kg8);
            rsn = *(const s16x8*)(sinb + (size_t)(p + krow) * 64 + kg8);
        } else {
            const u16* kp2 = Kn + (size_t)krow * 128 + kg8;
            rkn0 = *(const s16x8*)kp2;
            rkn1 = *(const s16x8*)(kp2 + 64);
        }
        rv0 = *(const s16x8*)(Vbase + (size_t)vr * TTOT + p + vc8);
        rv1 = *(const s16x8*)(Vbase + (size_t)(vr + 64) * TTOT + p + vc8);
        rm  = *(const s16x8*)(mrow + (size_t)(p + mpos) * 64 + mq8);
        tin = t;
        __builtin_amdgcn_sched_barrier(0);   // pin load issue here
    };
    auto stKM = [&]() {       // overwrites single-buffered Ksh/Msh
        if (tin < 64) {
            float ss = rx0.x*rx0.x + rx0.y*rx0.y + rx0.z*rx0.z + rx0.w*rx0.w
                     + rx1.x*rx1.x + rx1.y*rx1.y + rx1.z*rx1.z + rx1.w*rx1.w
                     + rx2.x*rx2.x + rx2.y*rx2.y + rx2.z*rx2.z + rx2.w*rx2.w
                     + rx3.x*rx3.x + rx3.y*rx3.y + rx3.z*rx3.z + rx3.w*rx3.w;
            ss += __shfl_xor(ss, 1);
            ss += __shfl_xor(ss, 2);
            ss += __shfl_xor(ss, 4);
            const float rr = rsqrtf(ss * (1.0f / 128.0f) + 1e-6f);
            s16x8 klo, khi;
#define KROPE(i, xl, xh, wl, wh)                                     \
            {                                                        \
                const float nlo = xl * rr * wl, nhi = xh * rr * wh;  \
                const float c = bf2f((u16)rcs[i]), sn = bf2f((u16)rsn[i]); \
                klo[i] = (short)f2bf(nlo * c - nhi * sn);            \
                khi[i] = (short)f2bf(nhi * c + nlo * sn);            \
            }
            KROPE(0, rx0.x, rx2.x, w0.x, w2.x)
            KROPE(1, rx0.y, rx2.y, w0.y, w2.y)
            KROPE(2, rx0.z, rx2.z, w0.z, w2.z)
            KROPE(3, rx0.w, rx2.w, w0.w, w2.w)
            KROPE(4, rx1.x, rx3.x, w1.x, w3.x)
            KROPE(5, rx1.y, rx3.y, w1.y, w3.y)
            KROPE(6, rx1.z, rx3.z, w1.z, w3.z)
            KROPE(7, rx1.w, rx3.w, w1.w, w3.w)
#undef KROPE
            *(s16x8*)(Ksh + krow * 132 + kg8)      = klo;
            *(s16x8*)(Ksh + krow * 132 + 64 + kg8) = khi;
        } else {
            *(s16x8*)(Ksh + krow * 132 + kg8)      = rkn0;
            *(s16x8*)(Ksh + krow * 132 + 64 + kg8) = rkn1;
        }
        *(s16x8*)(Msh + mpos * 72 + mq8) = rm;
    };
    auto stV = [&](int buf) {
        *(s16x8*)(Vsh[buf] + vr * 68 + vc8) = rv0;
        *(s16x8*)(Vsh[buf] + (vr + 64) * 68 + vc8) = rv1;
    };

    // prologue
    ld(t0);
    stKM();
    stV(0);
    __syncthreads();
    if (t0 + 1 < t1) ld(t0 + 1);

    int cur = 0;
    for (int t = t0; t < t1; ++t) {
        // ---- QK from Ksh (single buf) ----
        f32x4 sc[2][4];
#pragma unroll
        for (int mt = 0; mt < 2; ++mt)
#pragma unroll
            for (int nt = 0; nt < 4; ++nt) sc[mt][nt] = (f32x4){0.f, 0.f, 0.f, 0.f};
        __builtin_amdgcn_s_setprio(1);
#pragma unroll
        for (int nt = 0; nt < 4; ++nt) {
#pragma unroll
            for (int ks = 0; ks < 4; ++ks) {
                bf16x8 bk = *(const bf16x8*)(Ksh + (nt * 16 + l15) * 132 + ks * 32 + l4 * 8);
                sc[0][nt] = mfma16(aq[0][ks], bk, sc[0][nt]);
                sc[1][nt] = mfma16(aq[1][ks], bk, sc[1][nt]);
            }
        }
        __builtin_amdgcn_s_setprio(0);

        // ---- softmax from Msh (single buf): p = exp2(sc + msh) ----
#pragma unroll
        for (int mt = 0; mt < 2; ++mt) {
#pragma unroll
            for (int nt = 0; nt < 4; ++nt) {
                u16x4 m4 = *(const u16x4*)(Msh + (nt * 16 + l15) * 72 + qbase + mt * 16 + l4 * 4);
#pragma unroll
                for (int r = 0; r < 4; ++r)
                    sc[mt][nt][r] = exp2f(sc[mt][nt][r] + bf2f(m4[r]));
            }
        }

        __syncthreads();   // barrier1: all waves done with Ksh/Msh reads

        // ---- overwrite Ksh/Msh with tile t+1; stage V(t+1) into dbuf ----
        if (t + 1 < t1) { stKM(); stV(cur ^ 1); }

        // ---- PV from Vsh[cur] (dbuf); P roundtrip per-wave ----
#pragma unroll
        for (int ks = 0; ks < 2; ++ks) {
#pragma unroll
            for (int mt = 0; mt < 2; ++mt)
#pragma unroll
                for (int r = 0; r < 4; ++r) {
                    P[(mt * 16 + l4 * 4 + r) * 36 + l15]      = f2bf(sc[mt][ks * 2 + 0][r]);
                    P[(mt * 16 + l4 * 4 + r) * 36 + 16 + l15] = f2bf(sc[mt][ks * 2 + 1][r]);
                }
            bf16x8 ap0 = *(const bf16x8*)(P + (l15) * 36 + l4 * 8);
            bf16x8 ap1 = *(const bf16x8*)(P + (16 + l15) * 36 + l4 * 8);
            __builtin_amdgcn_s_setprio(1);
#pragma unroll
            for (int nt = 0; nt < 8; ++nt) {
                bf16x8 bv = *(const bf16x8*)(Vsh[cur] + (nt * 16 + l15) * 68 + ks * 32 + l4 * 8);
                o[0][nt] = mfma16(ap0, bv, o[0][nt]);
                o[1][nt] = mfma16(ap1, bv, o[1][nt]);
            }
            ol[0] = mfma16(ap0, bones, ol[0]);
            ol[1] = mfma16(ap1, bones, ol[1]);
            __builtin_amdgcn_s_setprio(0);
        }

        __syncthreads();   // barrier2: Ksh/Msh/Vsh writes visible
        if (t + 2 < t1) ld(t + 2);
        cur ^= 1;
    }

    // coalesced epilogue: Opart chunk per (b,h,s) = [qh][mt][nt][lane][r] u16
    {
        u16* ob = Opart + ((size_t)((b * 16 + h) * S + s)) * 8192;
#pragma unroll
        for (int mt = 0; mt < 2; ++mt)
#pragma unroll
            for (int nt = 0; nt < 8; ++nt) {
                u16x4 v;
#pragma unroll
                for (int r = 0; r < 4; ++r) v[r] = f2bf(o[mt][nt][r]);
                *(u16x4*)(ob + (((qh * 2 + mt) * 8 + nt) * 64 + lane) * 4) = v;
            }
        if (l15 == 0) {
#pragma unroll
            for (int mt = 0; mt < 2; ++mt)
#pragma unroll
                for (int r = 0; r < 4; ++r) {
                    const int q = qbase + mt * 16 + l4 * 4 + r;
                    lsum[((size_t)((b * 16 + h) * 64 + q)) * S + s] = ol[mt][r];
                }
        }
    }
}

// ---------------- merge splits -> attn (B,K,NH*HD) bf16 -------------------
template <int S>
__global__ __launch_bounds__(256) void merge_kernel(
    const u16* __restrict__ Opart, const float* __restrict__ lsum, u16* __restrict__ attnb)
{
    const int wid = blockIdx.x * 4 + (threadIdx.x >> 6);   // (b*16+h)*2 + qh
    const int lane = threadIdx.x & 63;
    const int l15 = lane & 15, l4 = lane >> 4;
    const int qh = wid & 1, bh = wid >> 1;
    const int h = bh & 15, b = bh >> 4;

    float L = 0.f;
    {
        const float* lr = lsum + ((size_t)bh * 64 + qh * 32 + (lane & 31)) * S;
#pragma unroll
        for (int s2 = 0; s2 < S; ++s2) L += lr[s2];
    }
    const float invL = 1.0f / L;

    float acc[2][8][4];
#pragma unroll
    for (int mt = 0; mt < 2; ++mt)
#pragma unroll
        for (int nt = 0; nt < 8; ++nt)
#pragma unroll
            for (int r = 0; r < 4; ++r) acc[mt][nt][r] = 0.f;

    for (int s2 = 0; s2 < S; ++s2) {
        const u16* ob = Opart + ((size_t)(bh * S + s2)) * 8192;
#pragma unroll
        for (int mt = 0; mt < 2; ++mt)
#pragma unroll
            for (int nt = 0; nt < 8; ++nt) {
                u16x4 v = *(const u16x4*)(ob + (((qh * 2 + mt) * 8 + nt) * 64 + lane) * 4);
#pragma unroll
                for (int r = 0; r < 4; ++r) acc[mt][nt][r] += bf2f(v[r]);
            }
    }

#pragma unroll
    for (int mt = 0; mt < 2; ++mt)
#pragma unroll
        for (int r = 0; r < 4; ++r) {
            const float wl = __shfl(invL, mt * 16 + l4 * 4 + r);
            const int q = qh * 32 + mt * 16 + l4 * 4 + r;
            u16* dst = attnb + (size_t)(b * 64 + q) * 2048 + h * 128;
#pragma unroll
            for (int nt = 0; nt < 8; ++nt)
                dst[nt * 16 + l15] = f2bf(acc[mt][nt][r] * wl);
        }
}

// ---------------- launch ----------------
extern "C" void kernel_launch(void* const* d_in, const int* in_sizes, int n_in,
                              void* d_out, int out_size, void* d_ws, size_t ws_size,
                              hipStream_t stream)
{
    (void)in_sizes; (void)n_in; (void)out_size; (void)ws_size;
    const float* hs   = (const float*)d_in[0];
    const float* ctxk = (const float*)d_in[1];
    const float* ctxv = (const float*)d_in[2];
    const float* mask = (const float*)d_in[3];
    const float* cosT = (const float*)d_in[4];
    const float* sinT = (const float*)d_in[5];
    const float* wq   = (const float*)d_in[6];
    const float* wk   = (const float*)d_in[7];
    const float* wv   = (const float*)d_in[8];
    const float* wo   = (const float*)d_in[9];
    const float* qnw  = (const float*)d_in[10];
    const float* knw  = (const float*)d_in[11];

    const int S = 16;   // 512 attn blocks -> 2 blocks/CU at 79.4KB LDS

    char* ws = (char*)d_ws;
    size_t off = 0;
    auto carve = [&](size_t bytes) -> void* {
        void* p = ws + off;
        off += (bytes + 255) & ~(size_t)255;
        return p;
    };
    u16*   Qb    = (u16*)carve((size_t)BB * NH * 64 * 128 * 2);         // 2.1 MB
    u16*   VtG   = (u16*)carve((size_t)BB * NKV * TTOT * 128 * 2);      // 34.1 MB
    u16*   Opart = (u16*)carve((size_t)BB * NH * S * 8192 * 2);         // 33.6 MB
    float* lsumb = (float*)carve((size_t)BB * NH * 64 * S * 4);         // 0.52 MB
    u16*   attnb = (u16*)carve((size_t)512 * 2048 * 2);                 // 2.1 MB
    u16*   wob   = (u16*)carve((size_t)2048 * 2048 * 2);                // 8.4 MB
    u16*   wqkvb = (u16*)carve((size_t)3072 * 2048 * 2);                // 12.6 MB
    u16*   knb   = (u16*)carve((size_t)BB * NKV * 64 * 128 * 2);        // 0.52 MB
    u16*   vnb   = (u16*)carve((size_t)BB * NKV * 64 * 128 * 2);        // 0.52 MB
    u16*   maskT = (u16*)carve((size_t)BB * TTOT * 64 * 2);             // 4.3 MB
    u16*   cosb  = (u16*)carve((size_t)TTOT * 64 * 2);                  // 0.53 MB
    u16*   sinb  = (u16*)carve((size_t)TTOT * 64 * 2);                  // 0.53 MB
    // ~99.8 MB. Time-multiplexed aliases (stream-ordered liveness):
    float* qkvp = (float*)VtG;    // qkv split-K partials; dead before build_ctx_v
    u16*   hsb  = (u16*)Opart;    // bf16 hs; dead before attn_partial
    float* outp = (float*)Opart;  // out partials; Opart dead after merge

    // 1) cast weights/activations + bf16 cos/sin half-tables; fold mask
    cast_all<<<5892, 256, 0, stream>>>(wq, wk, wv, wo, hs, cosT, sinT,
                                       wqkvb, wob, hsb, cosb, sinb);
    prep_mask<<<520, 256, 0, stream>>>(mask, maskT);
    // 2) QKV projection (bf16, split-K x4, XCD swizzle)
    gemm_qkv_sk<<<1536, 256, 0, stream>>>(hsb, wqkvb, qkvp);
    // 3) fused reduce + RMSNorm/RoPE/cast -> Qb, k-noise, v-noise
    finalize_qkv<<<1536, 256, 0, stream>>>(qkvp, qnw, knw, cosT, sinT, Qb, knb, vnb);
    // 4) ctx V^T (LDS-staged transpose); K build is FUSED into attn
    build_ctx_v<<<2080, 256, 0, stream>>>(ctxv, vnb, VtG);
    // 5) flash attention (512 thr, single-buf K/M, 2 blk/CU) + merge
    attn_partial<16><<<dim3(16, NKV, BB), 512, 0, stream>>>(
        Qb, ctxk, knw, cosb, sinb, knb, VtG, maskT, Opart, lsumb);
    merge_kernel<16><<<64, 256, 0, stream>>>(Opart, lsumb, attnb);
    // 6) output projection (bf16, split-K x4, XCD swizzle) -> reduce
    gemm_out_sk<<<1024, 256, 0, stream>>>(attnb, wob, outp);
    reduce4<<<1024, 256, 0, stream>>>(outp, (float*)d_out, (size_t)512 * 2048);
}

// Round 17
// 140.216 us; speedup vs baseline: 1.3323x; 1.2162x over previous
//
#include <hip/hip_runtime.h>

// ---------------- problem constants ----------------
#define BB   8
#define KQ   64
#define HDIM 2048
#define NH   16
#define NKV  4
#define HD   128
#define CTX  4096
#define TTOT 4160      // CTX + KQ
#define NTILES 65      // TTOT / 64
#define LOG2E 1.4426950408889634f
#define SCALE 0.08838834764831845f  // 1/sqrt(128)
#define QSCALE (SCALE * LOG2E)      // folded into Q; exp2-domain softmax
// |q.k| <= 128 after RMS-norm => |sc| <= 128*QSCALE = 16.33. Fixed softmax max.
#define MFIX 16.34f

typedef unsigned short u16;
typedef unsigned int   u32;
typedef __attribute__((ext_vector_type(8))) short  s16x8;   // bf16 storage
typedef __attribute__((ext_vector_type(4))) unsigned short u16x4;
typedef __attribute__((ext_vector_type(4))) float  f32x4;
typedef __bf16 bf16x8 __attribute__((ext_vector_type(8)));  // MFMA operand

__device__ __forceinline__ u16 f2bf(float f) {              // HW RNE cvt
    union { __bf16 h; u16 u; } v; v.h = (__bf16)f; return v.u;
}
__device__ __forceinline__ float bf2f(u16 u) {
    union { float f; u32 u; } v; v.u = ((u32)u) << 16;
    return v.f;
}
__device__ __forceinline__ u32 pack2(float a, float b) {
    return (u32)f2bf(a) | ((u32)f2bf(b) << 16);
}
__device__ __forceinline__ f32x4 mfma16(bf16x8 a, bf16x8 b, f32x4 c) {
    return __builtin_amdgcn_mfma_f32_16x16x32_bf16(a, b, c, 0, 0, 0);
}

// ---------------- fused f32 -> bf16 cast of 5 tensors + cos/sin tables ----
__global__ __launch_bounds__(256) void cast_all(
    const float* __restrict__ wq, const float* __restrict__ wk,
    const float* __restrict__ wv, const float* __restrict__ wo,
    const float* __restrict__ hs, const float* __restrict__ cosT,
    const float* __restrict__ sinT,
    u16* __restrict__ wqkvb, u16* __restrict__ wob, u16* __restrict__ hsb,
    u16* __restrict__ cosb, u16* __restrict__ sinb)
{
    const int i = blockIdx.x * 256 + threadIdx.x;
    const float* src; u16* dst;
    if (i < 524288)        { src = wq + (size_t)i * 8;             dst = wqkvb + (size_t)i * 8; }
    else if (i < 655360)   { src = wk + (size_t)(i - 524288) * 8;  dst = wqkvb + (size_t)i * 8; }
    else if (i < 786432)   { src = wv + (size_t)(i - 655360) * 8;  dst = wqkvb + (size_t)i * 8; }
    else if (i < 1310720)  { src = wo + (size_t)(i - 786432) * 8;  dst = wob + (size_t)(i - 786432) * 8; }
    else if (i < 1441792)  { src = hs + (size_t)(i - 1310720) * 8; dst = hsb + (size_t)(i - 1310720) * 8; }
    else if (i < 1475072)  { const int l = (i - 1441792) * 8;
                             src = cosT + (size_t)(l >> 6) * 128 + (l & 63); dst = cosb + l; }
    else                   { const int l = (i - 1475072) * 8;
                             src = sinT + (size_t)(l >> 6) * 128 + (l & 63); dst = sinb + l; }
    float4 a = *(const float4*)src;
    float4 b = *(const float4*)(src + 4);
    s16x8 v;
    v[0]=(short)f2bf(a.x); v[1]=(short)f2bf(a.y); v[2]=(short)f2bf(a.z); v[3]=(short)f2bf(a.w);
    v[4]=(short)f2bf(b.x); v[5]=(short)f2bf(b.y); v[6]=(short)f2bf(b.z); v[7]=(short)f2bf(b.w);
    *(s16x8*)dst = v;
}

// ---------------- mask pre-transpose: maskT[b][pos][q] bf16 ---------------
__global__ __launch_bounds__(256) void prep_mask(
    const float* __restrict__ mask, u16* __restrict__ maskT)
{
    __shared__ float T[64 * 65];
    const int pt = blockIdx.x % 65, b = blockIdx.x / 65;
    const int p0 = pt * 64;
    {
        const int q = threadIdx.x >> 2, pg = (threadIdx.x & 3) * 16;
        const float* src = mask + ((size_t)b * 64 + q) * TTOT + p0 + pg;
#pragma unroll
        for (int v4 = 0; v4 < 4; ++v4) {
            float4 v = *(const float4*)(src + v4 * 4);
            T[q * 65 + pg + v4 * 4 + 0] = fmaf(v.x, LOG2E, -MFIX);
            T[q * 65 + pg + v4 * 4 + 1] = fmaf(v.y, LOG2E, -MFIX);
            T[q * 65 + pg + v4 * 4 + 2] = fmaf(v.z, LOG2E, -MFIX);
            T[q * 65 + pg + v4 * 4 + 3] = fmaf(v.w, LOG2E, -MFIX);
        }
    }
    __syncthreads();
    {
        const int pos = threadIdx.x >> 2, qg = (threadIdx.x & 3) * 16;
        u16* dst = maskT + ((size_t)b * TTOT + p0 + pos) * 64 + qg;
#pragma unroll
        for (int h8 = 0; h8 < 2; ++h8) {
            s16x8 v;
#pragma unroll
            for (int je = 0; je < 8; ++je)
                v[je] = (short)f2bf(T[(qg + h8 * 8 + je) * 65 + pos]);
            *(s16x8*)(dst + h8 * 8) = v;
        }
    }
}

// ---------------- 64x64-tile GEMM core, bf16 inputs (padded LDS) ----------
__device__ __forceinline__ void gemm64_body(
    const u16* __restrict__ Ab, const u16* __restrict__ Bb,
    float* __restrict__ Cb, const int ldc, const int ldk, const int Klen,
    u16* Ash, u16* Bsh)
{
    const int tid = threadIdx.x, lane = tid & 63;
    const int w = tid >> 6, wm = w >> 1, wn = w & 1;
    const int l15 = lane & 15, l4 = lane >> 4;
    const int srow = tid >> 2, scol = (tid & 3) * 16;

    f32x4 acc[2][2];
#pragma unroll
    for (int i = 0; i < 2; ++i)
#pragma unroll
        for (int j = 0; j < 2; ++j) acc[i][j] = (f32x4){0.f, 0.f, 0.f, 0.f};

    const u16* ap = Ab + (size_t)srow * ldk + scol;
    const u16* bp = Bb + (size_t)srow * ldk + scol;
    s16x8 ra0 = *(const s16x8*)ap, ra1 = *(const s16x8*)(ap + 8);
    s16x8 rb0 = *(const s16x8*)bp, rb1 = *(const s16x8*)(bp + 8);
    __builtin_amdgcn_sched_barrier(0);

    for (int k0 = 0; k0 < Klen; k0 += 64) {
        __syncthreads();
        *(s16x8*)(Ash + srow * 72 + scol)     = ra0;
        *(s16x8*)(Ash + srow * 72 + scol + 8) = ra1;
        *(s16x8*)(Bsh + srow * 72 + scol)     = rb0;
        *(s16x8*)(Bsh + srow * 72 + scol + 8) = rb1;
        __syncthreads();
        if (k0 + 64 < Klen) {
            const u16* ap2 = ap + k0 + 64;
            const u16* bp2 = bp + k0 + 64;
            ra0 = *(const s16x8*)ap2; ra1 = *(const s16x8*)(ap2 + 8);
            rb0 = *(const s16x8*)bp2; rb1 = *(const s16x8*)(bp2 + 8);
            __builtin_amdgcn_sched_barrier(0);
        }
#pragma unroll
        for (int ks = 0; ks < 2; ++ks) {
            bf16x8 am[2], bb[2];
#pragma unroll
            for (int i = 0; i < 2; ++i) {
                am[i] = *(const bf16x8*)(Ash + (wm * 32 + i * 16 + l15) * 72 + ks * 32 + l4 * 8);
                bb[i] = *(const bf16x8*)(Bsh + (wn * 32 + i * 16 + l15) * 72 + ks * 32 + l4 * 8);
            }
#pragma unroll
            for (int i = 0; i < 2; ++i)
#pragma unroll
                for (int j = 0; j < 2; ++j)
                    acc[i][j] = mfma16(am[i], bb[j], acc[i][j]);
        }
    }

    float* Cw = Cb + (size_t)(wm * 32) * ldc + wn * 32;
#pragma unroll
    for (int i = 0; i < 2; ++i)
#pragma unroll
        for (int j = 0; j < 2; ++j)
#pragma unroll
            for (int r = 0; r < 4; ++r)
                Cw[(size_t)(i * 16 + l4 * 4 + r) * ldc + j * 16 + l15] = acc[i][j][r];
}

// QKV projection, split-K x4, XCD-chunked swizzle. 1D grid 1536.
__global__ __launch_bounds__(256) void gemm_qkv_sk(
    const u16* __restrict__ hsb, const u16* __restrict__ wqkvb,
    float* __restrict__ qkvp)
{
    __shared__ __align__(16) u16 Ash[64 * 72];
    __shared__ __align__(16) u16 Bsh[64 * 72];
    const int wid = (blockIdx.x & 7) * 192 + (blockIdx.x >> 3);
    const int y = wid >> 5, rem = wid & 31, kc = rem >> 3, x = rem & 7;
    const int koff = kc * 512;
    const u16* Ab = hsb + (size_t)x * 64 * HDIM + koff;
    const u16* Bb = wqkvb + (size_t)y * 64 * HDIM + koff;
    float* Cb = qkvp + (size_t)kc * 512 * 3072 + (size_t)x * 64 * 3072 + y * 64;
    gemm64_body(Ab, Bb, Cb, 3072, HDIM, 512, Ash, Bsh);
}

// Output projection, split-K x4, XCD-chunked swizzle. 1D grid 1024.
__global__ __launch_bounds__(256) void gemm_out_sk(
    const u16* __restrict__ attnb, const u16* __restrict__ wob,
    float* __restrict__ outp)
{
    __shared__ __align__(16) u16 Ash[64 * 72];
    __shared__ __align__(16) u16 Bsh[64 * 72];
    const int wid = (blockIdx.x & 7) * 128 + (blockIdx.x >> 3);
    const int y = wid >> 5, rem = wid & 31, kc = rem >> 3, x = rem & 7;
    const int koff = kc * 512;
    const u16* Ab = attnb + (size_t)x * 64 * HDIM + koff;
    const u16* Bb = wob + (size_t)y * 64 * HDIM + koff;
    float* Cb = outp + (size_t)kc * 512 * 2048 + (size_t)x * 64 * 2048 + y * 64;
    gemm64_body(Ab, Bb, Cb, 2048, HDIM, 512, Ash, Bsh);
}

// sum 4 partial chunks -> out (float4 per thread), deterministic.
__global__ __launch_bounds__(256) void reduce4(
    const float* __restrict__ p, float* __restrict__ out, const size_t chunk)
{
    const size_t i = ((size_t)blockIdx.x * 256 + threadIdx.x) * 4;
    float4 a = *(const float4*)(p + i);
    float4 b = *(const float4*)(p + i + chunk);
    float4 c = *(const float4*)(p + i + 2 * chunk);
    float4 d = *(const float4*)(p + i + 3 * chunk);
    float4 r;
    r.x = (a.x + b.x) + (c.x + d.x);
    r.y = (a.y + b.y) + (c.y + d.y);
    r.z = (a.z + b.z) + (c.z + d.z);
    r.w = (a.w + b.w) + (c.w + d.w);
    *(float4*)(out + i) = r;
}

// ---------------- RMSNorm+RoPE on in-register values (half-wave) ----------
__device__ __forceinline__ void norm_rope_vals(
    float2 xa, float2 xb, const float* __restrict__ wgt,
    const float* __restrict__ cosT, const float* __restrict__ sinT,
    int pos, int j, float outScale, u16* __restrict__ dst)
{
    float ss = xa.x * xa.x + xa.y * xa.y + xb.x * xb.x + xb.y * xb.y;
#pragma unroll
    for (int m = 1; m < 32; m <<= 1) ss += __shfl_xor(ss, m);
    const float rr = rsqrtf(ss * (1.0f / 128.0f) + 1e-6f);
    float2 wa = *(const float2*)(wgt + 2 * j);
    float2 wb = *(const float2*)(wgt + 2 * j + 64);
    float2 ca = *(const float2*)(cosT + (size_t)pos * 128 + 2 * j);
    float2 sa = *(const float2*)(sinT + (size_t)pos * 128 + 2 * j);
    const float nax = xa.x * rr * wa.x, nay = xa.y * rr * wa.y;
    const float nbx = xb.x * rr * wb.x, nby = xb.y * rr * wb.y;
    const float lox = (nax * ca.x - nbx * sa.x) * outScale;
    const float loy = (nay * ca.y - nby * sa.y) * outScale;
    const float hix = (nbx * ca.x + nax * sa.x) * outScale;
    const float hiy = (nby * ca.y + nay * sa.y) * outScale;
    ((u32*)dst)[j]      = pack2(lox, loy);
    ((u32*)dst)[j + 32] = pack2(hix, hiy);
}

// ---------------- fused split-K reduce + RMSNorm/RoPE/cast ----------------
__global__ __launch_bounds__(256) void finalize_qkv(
    const float* __restrict__ qkvp, const float* __restrict__ qw,
    const float* __restrict__ kw, const float* __restrict__ cosT,
    const float* __restrict__ sinT,
    u16* __restrict__ Qb, u16* __restrict__ knb, u16* __restrict__ vnb)
{
    const int unit = blockIdx.x * 8 + (threadIdx.x >> 5);
    const int j = threadIdx.x & 31;
    const int slot = unit % 24, bq = unit / 24;
    const int b = bq >> 6, q = bq & 63;
    const int col0 = (slot < 16) ? slot * 128
                   : (slot < 20) ? 2048 + (slot - 16) * 128
                                 : 2560 + (slot - 20) * 128;
    const float* base = qkvp + (size_t)bq * 3072 + col0;

    float2 xa = {0.f, 0.f}, xb = {0.f, 0.f};
#pragma unroll
    for (int kc = 0; kc < 4; ++kc) {
        const float* p = base + (size_t)kc * 512 * 3072;
        float2 a = *(const float2*)(p + 2 * j);
        float2 c = *(const float2*)(p + 2 * j + 64);
        xa.x += a.x; xa.y += a.y; xb.x += c.x; xb.y += c.y;
    }

    if (slot < 16) {
        norm_rope_vals(xa, xb, qw, cosT, sinT, CTX + q, j, QSCALE,
                       Qb + ((size_t)((b * 16 + slot) * 64 + q)) * 128);
    } else if (slot < 20) {
        norm_rope_vals(xa, xb, kw, cosT, sinT, CTX + q, j, 1.0f,
                       knb + ((size_t)((b * 4 + (slot - 16)) * 64 + q)) * 128);
    } else {
        u16* dst = vnb + ((size_t)((b * 4 + (slot - 20)) * 64 + q)) * 128;
        ((u32*)dst)[j]      = pack2(xa.x, xa.y);
        ((u32*)dst)[j + 32] = pack2(xb.x, xb.y);
    }
}

// ---------------- ctx V^T build: LDS-staged transpose + vnb tail ----------
__global__ __launch_bounds__(256) void build_ctx_v(
    const float* __restrict__ ctxv, const u16* __restrict__ vnb,
    u16* __restrict__ VtG)
{
    __shared__ __align__(16) float Vt[64 * 130];
    const int bid = blockIdx.x;
    if (bid < 2048) {
        const int pt = bid & 63, kv = (bid >> 6) & 3, b = bid >> 8;
        const int p0 = pt * 64;
        const float* src = ctxv + ((size_t)(b * 4096 + p0) * 4 + kv) * 128;
#pragma unroll
        for (int it = 0; it < 8; ++it) {
            const int g = it * 256 + threadIdx.x;
            const int row = g >> 5, c4 = (g & 31) * 4;
            *(float4*)(&Vt[row * 130 + c4]) = *(const float4*)(src + (size_t)row * 512 + c4);
        }
        __syncthreads();
        const int d = threadIdx.x & 127, half = threadIdx.x >> 7;
        u16* dst = VtG + ((size_t)(b * 4 + kv) * 128 + d) * TTOT + p0 + half * 32;
#pragma unroll
        for (int q8 = 0; q8 < 4; ++q8) {
            s16x8 v;
#pragma unroll
            for (int je = 0; je < 8; ++je)
                v[je] = (short)f2bf(Vt[(half * 32 + q8 * 8 + je) * 130 + d]);
            *(s16x8*)(dst + q8 * 8) = v;
        }
    } else {
        const int idx = bid - 2048;   // b*4+kv
        const u16* src = vnb + (size_t)idx * 64 * 128;
        u16* dstb = VtG + (size_t)idx * 128 * TTOT + 4096;
        const int d = threadIdx.x & 127, qh = threadIdx.x >> 7;
        u16* dst = dstb + (size_t)d * TTOT + qh * 32;
#pragma unroll
        for (int q8 = 0; q8 < 4; ++q8) {
            s16x8 v;
#pragma unroll
            for (int je = 0; je < 8; ++je)
                v[je] = (short)src[(size_t)(qh * 32 + q8 * 8 + je) * 128 + d];
            *(s16x8*)(dst + q8 * 8) = v;
        }
    }
}

// ---------------- flash attention: round-14 schedule + conflict-free pads -
// Round-15 (16 waves) and round-16 (single-buf K/M, 2 blk/CU) both
// regressed: 64-VGPR spills resp. KROPE moved onto the serial path.
// This is the round-14 double-buffered schedule (best known, 56us)
// with the ONLY validated round-16 finding grafted in: pads 132/68/36
// (bank conflicts 2.93M -> ~0.5M measured in isolation).
template <int S>
__global__ __launch_bounds__(512, 2) void attn_partial(
    const u16* __restrict__ Qb, const float* __restrict__ ctxk,
    const float* __restrict__ knw, const u16* __restrict__ cosb,
    const u16* __restrict__ sinb, const u16* __restrict__ knb,
    const u16* __restrict__ VtG, const u16* __restrict__ maskT,
    u16* __restrict__ Opart, float* __restrict__ lsum)
{
    __shared__ __align__(16) u16 Ksh[2][64 * 132];   // K [pos][d], dbuf
    __shared__ __align__(16) u16 Vsh[2][128 * 68];   // V^T [d][pos], dbuf
    __shared__ __align__(16) u16 Msh[2][64 * 72];    // maskT tile [pos][q]
    __shared__ __align__(16) u16 Psh[8][32 * 36];    // per-wave P chunk

    const int s = blockIdx.x, kv = blockIdx.y, b = blockIdx.z;
    const int tid = threadIdx.x, lane = tid & 63, w = tid >> 6;
    const int h = kv * 4 + (w >> 1);
    const int qh = w & 1, qbase = qh * 32;
    const int l15 = lane & 15, l4 = lane >> 4;
    const int t0 = (NTILES * s) / S, t1 = (NTILES * (s + 1)) / S;

    const int krow = tid >> 3, kg8 = (tid & 7) * 8;
    const int vr = tid >> 3, vc8 = (tid & 7) * 8;
    const int mpos = tid >> 3, mq8 = (tid & 7) * 8;

    const float4 w0 = *(const float4*)(knw + kg8);
    const float4 w1 = *(const float4*)(knw + kg8 + 4);
    const float4 w2 = *(const float4*)(knw + kg8 + 64);
    const float4 w3 = *(const float4*)(knw + kg8 + 68);

    bf16x8 aq[2][4];
    {
        const u16* qb = Qb + ((size_t)((b * 16 + h) * 64 + qbase)) * 128;
#pragma unroll
        for (int mt = 0; mt < 2; ++mt)
#pragma unroll
            for (int ks = 0; ks < 4; ++ks)
                aq[mt][ks] = *(const bf16x8*)(qb + (mt * 16 + l15) * 128 + ks * 32 + l4 * 8);
    }

    bf16x8 bones;   // col-0 ones -> P row sums via MFMA
    {
        __bf16 e = (l15 == 0) ? (__bf16)1.0f : (__bf16)0.0f;
#pragma unroll
        for (int i = 0; i < 8; ++i) bones[i] = e;
    }

    f32x4 o[2][8], ol[2];
#pragma unroll
    for (int mt = 0; mt < 2; ++mt) {
        ol[mt] = (f32x4){0.f, 0.f, 0.f, 0.f};
#pragma unroll
        for (int nt = 0; nt < 8; ++nt) o[mt][nt] = (f32x4){0.f, 0.f, 0.f, 0.f};
    }

    const u16* Kn    = knb + (size_t)(b * 4 + kv) * 64 * 128;
    const u16* Vbase = VtG + (size_t)(b * 4 + kv) * 128 * TTOT;
    const u16* mrow  = maskT + (size_t)b * TTOT * 64;
    u16* P = Psh[w];

    float4 rx0, rx1, rx2, rx3;          // raw K f32 (tiles 0..63)
    s16x8 rcs, rsn;                     // bf16 cos/sin slice
    s16x8 rkn0, rkn1;                   // knb bf16 (tile 64)
    s16x8 rv0, rv1, rm;
    int tin = -1;

    auto ld = [&](int t) {
        const int p = t * 64;
        if (t < 64) {
            const float* kp_ = ctxk + (((size_t)(b * 4096 + p + krow)) * 4 + kv) * 128 + kg8;
            rx0 = *(const float4*)kp_;        rx1 = *(const float4*)(kp_ + 4);
            rx2 = *(const float4*)(kp_ + 64); rx3 = *(const float4*)(kp_ + 68);
            rcs = *(const s16x8*)(cosb + (size_t)(p + krow) * 64 + kg8);
            rsn = *(const s16x8*)(sinb + (size_t)(p + krow) * 64 + kg8);
        } else {
            const u16* kp2 = Kn + (size_t)krow * 128 + kg8;
            rkn0 = *(const s16x8*)kp2;
            rkn1 = *(const s16x8*)(kp2 + 64);
        }
        rv0 = *(const s16x8*)(Vbase + (size_t)vr * TTOT + p + vc8);
        rv1 = *(const s16x8*)(Vbase + (size_t)(vr + 64) * TTOT + p + vc8);
        rm  = *(const s16x8*)(mrow + (size_t)(p + mpos) * 64 + mq8);
        tin = t;
        __builtin_amdgcn_sched_barrier(0);   // pin load issue here
    };
    auto st = [&](int buf) {
        if (tin < 64) {
            float ss = rx0.x*rx0.x + rx0.y*rx0.y + rx0.z*rx0.z + rx0.w*rx0.w
                     + rx1.x*rx1.x + rx1.y*rx1.y + rx1.z*rx1.z + rx1.w*rx1.w
                     + rx2.x*rx2.x + rx2.y*rx2.y + rx2.z*rx2.z + rx2.w*rx2.w
                     + rx3.x*rx3.x + rx3.y*rx3.y + rx3.z*rx3.z + rx3.w*rx3.w;
            ss += __shfl_xor(ss, 1);
            ss += __shfl_xor(ss, 2);
            ss += __shfl_xor(ss, 4);
            const float rr = rsqrtf(ss * (1.0f / 128.0f) + 1e-6f);
            s16x8 klo, khi;
#define KROPE(i, xl, xh, wl, wh)                                     \
            {                                                        \
                const float nlo = xl * rr * wl, nhi = xh * rr * wh;  \
                const float c = bf2f((u16)rcs[i]), sn = bf2f((u16)rsn[i]); \
                klo[i] = (short)f2bf(nlo * c - nhi * sn);            \
                khi[i] = (short)f2bf(nhi * c + nlo * sn);            \
            }
            KROPE(0, rx0.x, rx2.x, w0.x, w2.x)
            KROPE(1, rx0.y, rx2.y, w0.y, w2.y)
            KROPE(2, rx0.z, rx2.z, w0.z, w2.z)
            KROPE(3, rx0.w, rx2.w, w0.w, w2.w)
            KROPE(4, rx1.x, rx3.x, w1.x, w3.x)
            KROPE(5, rx1.y, rx3.y, w1.y, w3.y)
            KROPE(6, rx1.z, rx3.z, w1.z, w3.z)
            KROPE(7, rx1.w, rx3.w, w1.w, w3.w)
#undef KROPE
            *(s16x8*)(Ksh[buf] + krow * 132 + kg8)      = klo;
            *(s16x8*)(Ksh[buf] + krow * 132 + 64 + kg8) = khi;
        } else {
            *(s16x8*)(Ksh[buf] + krow * 132 + kg8)      = rkn0;
            *(s16x8*)(Ksh[buf] + krow * 132 + 64 + kg8) = rkn1;
        }
        *(s16x8*)(Vsh[buf] + vr * 68 + vc8) = rv0;
        *(s16x8*)(Vsh[buf] + (vr + 64) * 68 + vc8) = rv1;
        *(s16x8*)(Msh[buf] + mpos * 72 + mq8) = rm;
    };

    // prologue
    ld(t0);
    st(0);
    __syncthreads();
    if (t0 + 1 < t1) ld(t0 + 1);

    int cur = 0;
    for (int t = t0; t < t1; ++t) {
        // ---- compute tile t from buf[cur] ----
        f32x4 sc[2][4];
#pragma unroll
        for (int mt = 0; mt < 2; ++mt)
#pragma unroll
            for (int nt = 0; nt < 4; ++nt) sc[mt][nt] = (f32x4){0.f, 0.f, 0.f, 0.f};
        __builtin_amdgcn_s_setprio(1);
#pragma unroll
        for (int nt = 0; nt < 4; ++nt) {
#pragma unroll
            for (int ks = 0; ks < 4; ++ks) {
                bf16x8 bk = *(const bf16x8*)(Ksh[cur] + (nt * 16 + l15) * 132 + ks * 32 + l4 * 8);
                sc[0][nt] = mfma16(aq[0][ks], bk, sc[0][nt]);
                sc[1][nt] = mfma16(aq[1][ks], bk, sc[1][nt]);
            }
        }
        __builtin_amdgcn_s_setprio(0);

        // fixed-max softmax: p = exp2(sc + msh); msh pre-folded bf16 [pos][q]
#pragma unroll
        for (int mt = 0; mt < 2; ++mt) {
#pragma unroll
            for (int nt = 0; nt < 4; ++nt) {
                u16x4 m4 = *(const u16x4*)(Msh[cur] + (nt * 16 + l15) * 72 + qbase + mt * 16 + l4 * 4);
#pragma unroll
                for (int r = 0; r < 4; ++r)
                    sc[mt][nt][r] = exp2f(sc[mt][nt][r] + bf2f(m4[r]));
            }
        }

        // O += P V ; l += P 1
#pragma unroll
        for (int ks = 0; ks < 2; ++ks) {
#pragma unroll
            for (int mt = 0; mt < 2; ++mt)
#pragma unroll
                for (int r = 0; r < 4; ++r) {
                    P[(mt * 16 + l4 * 4 + r) * 36 + l15]      = f2bf(sc[mt][ks * 2 + 0][r]);
                    P[(mt * 16 + l4 * 4 + r) * 36 + 16 + l15] = f2bf(sc[mt][ks * 2 + 1][r]);
                }
            bf16x8 ap0 = *(const bf16x8*)(P + (l15) * 36 + l4 * 8);
            bf16x8 ap1 = *(const bf16x8*)(P + (16 + l15) * 36 + l4 * 8);
            __builtin_amdgcn_s_setprio(1);
#pragma unroll
            for (int nt = 0; nt < 8; ++nt) {
                bf16x8 bv = *(const bf16x8*)(Vsh[cur] + (nt * 16 + l15) * 68 + ks * 32 + l4 * 8);
                o[0][nt] = mfma16(ap0, bv, o[0][nt]);
                o[1][nt] = mfma16(ap1, bv, o[1][nt]);
            }
            ol[0] = mfma16(ap0, bones, ol[0]);
            ol[1] = mfma16(ap1, bones, ol[1]);
            __builtin_amdgcn_s_setprio(0);
        }

        // ---- stage tile t+1 into buf[cur^1]; prefetch t+2 ----
        if (t + 1 < t1) st(cur ^ 1);      // KROPE overlapped, off critical path
        __syncthreads();
        if (t + 2 < t1) ld(t + 2);
        cur ^= 1;
    }

    // coalesced epilogue: Opart chunk per (b,h,s) = [qh][mt][nt][lane][r] u16
    {
        u16* ob = Opart + ((size_t)((b * 16 + h) * S + s)) * 8192;
#pragma unroll
        for (int mt = 0; mt < 2; ++mt)
#pragma unroll
            for (int nt = 0; nt < 8; ++nt) {
                u16x4 v;
#pragma unroll
                for (int r = 0; r < 4; ++r) v[r] = f2bf(o[mt][nt][r]);
                *(u16x4*)(ob + (((qh * 2 + mt) * 8 + nt) * 64 + lane) * 4) = v;
            }
        if (l15 == 0) {
#pragma unroll
            for (int mt = 0; mt < 2; ++mt)
#pragma unroll
                for (int r = 0; r < 4; ++r) {
                    const int q = qbase + mt * 16 + l4 * 4 + r;
                    lsum[((size_t)((b * 16 + h) * 64 + q)) * S + s] = ol[mt][r];
                }
        }
    }
}

// ---------------- merge splits -> attn (B,K,NH*HD) bf16 -------------------
template <int S>
__global__ __launch_bounds__(256) void merge_kernel(
    const u16* __restrict__ Opart, const float* __restrict__ lsum, u16* __restrict__ attnb)
{
    const int wid = blockIdx.x * 4 + (threadIdx.x >> 6);   // (b*16+h)*2 + qh
    const int lane = threadIdx.x & 63;
    const int l15 = lane & 15, l4 = lane >> 4;
    const int qh = wid & 1, bh = wid >> 1;
    const int h = bh & 15, b = bh >> 4;

    float L = 0.f;
    {
        const float* lr = lsum + ((size_t)bh * 64 + qh * 32 + (lane & 31)) * S;
#pragma unroll
        for (int s2 = 0; s2 < S; ++s2) L += lr[s2];
    }
    const float invL = 1.0f / L;

    float acc[2][8][4];
#pragma unroll
    for (int mt = 0; mt < 2; ++mt)
#pragma unroll
        for (int nt = 0; nt < 8; ++nt)
#pragma unroll
            for (int r = 0; r < 4; ++r) acc[mt][nt][r] = 0.f;

    for (int s2 = 0; s2 < S; ++s2) {
        const u16* ob = Opart + ((size_t)(bh * S + s2)) * 8192;
#pragma unroll
        for (int mt = 0; mt < 2; ++mt)
#pragma unroll
            for (int nt = 0; nt < 8; ++nt) {
                u16x4 v = *(const u16x4*)(ob + (((qh * 2 + mt) * 8 + nt) * 64 + lane) * 4);
#pragma unroll
                for (int r = 0; r < 4; ++r) acc[mt][nt][r] += bf2f(v[r]);
            }
    }

#pragma unroll
    for (int mt = 0; mt < 2; ++mt)
#pragma unroll
        for (int r = 0; r < 4; ++r) {
            const float wl = __shfl(invL, mt * 16 + l4 * 4 + r);
            const int q = qh * 32 + mt * 16 + l4 * 4 + r;
            u16* dst = attnb + (size_t)(b * 64 + q) * 2048 + h * 128;
#pragma unroll
            for (int nt = 0; nt < 8; ++nt)
                dst[nt * 16 + l15] = f2bf(acc[mt][nt][r] * wl);
        }
}

// ---------------- launch ----------------
extern "C" void kernel_launch(void* const* d_in, const int* in_sizes, int n_in,
                              void* d_out, int out_size, void* d_ws, size_t ws_size,
                              hipStream_t stream)
{
    (void)in_sizes; (void)n_in; (void)out_size; (void)ws_size;
    const float* hs   = (const float*)d_in[0];
    const float* ctxk = (const float*)d_in[1];
    const float* ctxv = (const float*)d_in[2];
    const float* mask = (const float*)d_in[3];
    const float* cosT = (const float*)d_in[4];
    const float* sinT = (const float*)d_in[5];
    const float* wq   = (const float*)d_in[6];
    const float* wk   = (const float*)d_in[7];
    const float* wv   = (const float*)d_in[8];
    const float* wo   = (const float*)d_in[9];
    const float* qnw  = (const float*)d_in[10];
    const float* knw  = (const float*)d_in[11];

    const int S = 8;

    char* ws = (char*)d_ws;
    size_t off = 0;
    auto carve = [&](size_t bytes) -> void* {
        void* p = ws + off;
        off += (bytes + 255) & ~(size_t)255;
        return p;
    };
    u16*   Qb    = (u16*)carve((size_t)BB * NH * 64 * 128 * 2);         // 2.1 MB
    u16*   VtG   = (u16*)carve((size_t)BB * NKV * TTOT * 128 * 2);      // 34.1 MB
    u16*   Opart = (u16*)carve((size_t)BB * NH * S * 8192 * 2);         // 16.8 MB
    float* lsumb = (float*)carve((size_t)BB * NH * 64 * S * 4);         // 0.26 MB
    u16*   attnb = (u16*)carve((size_t)512 * 2048 * 2);                 // 2.1 MB
    u16*   wob   = (u16*)carve((size_t)2048 * 2048 * 2);                // 8.4 MB
    u16*   wqkvb = (u16*)carve((size_t)3072 * 2048 * 2);                // 12.6 MB
    u16*   knb   = (u16*)carve((size_t)BB * NKV * 64 * 128 * 2);        // 0.52 MB
    u16*   vnb   = (u16*)carve((size_t)BB * NKV * 64 * 128 * 2);        // 0.52 MB
    u16*   maskT = (u16*)carve((size_t)BB * TTOT * 64 * 2);             // 4.3 MB
    u16*   cosb  = (u16*)carve((size_t)TTOT * 64 * 2);                  // 0.53 MB
    u16*   sinb  = (u16*)carve((size_t)TTOT * 64 * 2);                  // 0.53 MB
    // ~82.8 MB. Time-multiplexed aliases (stream-ordered liveness):
    float* qkvp = (float*)VtG;    // qkv split-K partials; dead before build_ctx_v
    u16*   hsb  = (u16*)Opart;    // bf16 hs; dead before attn_partial
    float* outp = (float*)Opart;  // out partials; Opart dead after merge

    // 1) cast weights/activations + bf16 cos/sin half-tables; fold mask
    cast_all<<<5892, 256, 0, stream>>>(wq, wk, wv, wo, hs, cosT, sinT,
                                       wqkvb, wob, hsb, cosb, sinb);
    prep_mask<<<520, 256, 0, stream>>>(mask, maskT);
    // 2) QKV projection (bf16, split-K x4, XCD swizzle)
    gemm_qkv_sk<<<1536, 256, 0, stream>>>(hsb, wqkvb, qkvp);
    // 3) fused reduce + RMSNorm/RoPE/cast -> Qb, k-noise, v-noise
    finalize_qkv<<<1536, 256, 0, stream>>>(qkvp, qnw, knw, cosT, sinT, Qb, knb, vnb);
    // 4) ctx V^T (LDS-staged transpose); K build is FUSED into attn
    build_ctx_v<<<2080, 256, 0, stream>>>(ctxv, vnb, VtG);
    // 5) flash attention (round-14 schedule, conflict-free pads) + merge
    attn_partial<8><<<dim3(8, NKV, BB), 512, 0, stream>>>(
        Qb, ctxk, knw, cosb, sinb, knb, VtG, maskT, Opart, lsumb);
    merge_kernel<8><<<64, 256, 0, stream>>>(Opart, lsumb, attnb);
    // 6) output projection (bf16, split-K x4, XCD swizzle) -> reduce
    gemm_out_sk<<<1024, 256, 0, stream>>>(attnb, wob, outp);
    reduce4<<<1024, 256, 0, stream>>>(outp, (float*)d_out, (size_t)512 * 2048);
}

// Round 18
// 128.054 us; speedup vs baseline: 1.4588x; 1.0950x over previous
//
#include <hip/hip_runtime.h>

// ---------------- problem constants ----------------
#define BB   8
#define KQ   64
#define HDIM 2048
#define NH   16
#define NKV  4
#define HD   128
#define CTX  4096
#define TTOT 4160      // CTX + KQ
#define NTILES 65      // TTOT / 64
#define LOG2E 1.4426950408889634f
#define SCALE 0.08838834764831845f  // 1/sqrt(128)
#define QSCALE (SCALE * LOG2E)      // folded into Q; exp2-domain softmax
// |q.k| <= 128 after RMS-norm => |sc| <= 128*QSCALE = 16.33. Fixed softmax max.
#define MFIX 16.34f

typedef unsigned short u16;
typedef unsigned int   u32;
typedef __attribute__((ext_vector_type(8))) short  s16x8;   // bf16 storage
typedef __attribute__((ext_vector_type(4))) unsigned short u16x4;
typedef __attribute__((ext_vector_type(4))) float  f32x4;
typedef __bf16 bf16x8 __attribute__((ext_vector_type(8)));  // MFMA operand

__device__ __forceinline__ u16 f2bf(float f) {              // HW RNE cvt
    union { __bf16 h; u16 u; } v; v.h = (__bf16)f; return v.u;
}
__device__ __forceinline__ float bf2f(u16 u) {
    union { float f; u32 u; } v; v.u = ((u32)u) << 16;
    return v.f;
}
__device__ __forceinline__ u32 pack2(float a, float b) {
    return (u32)f2bf(a) | ((u32)f2bf(b) << 16);
}
__device__ __forceinline__ f32x4 mfma16(bf16x8 a, bf16x8 b, f32x4 c) {
    return __builtin_amdgcn_mfma_f32_16x16x32_bf16(a, b, c, 0, 0, 0);
}

// ---------------- fused f32 -> bf16 cast of 5 tensors + cos/sin tables ----
__global__ __launch_bounds__(256) void cast_all(
    const float* __restrict__ wq, const float* __restrict__ wk,
    const float* __restrict__ wv, const float* __restrict__ wo,
    const float* __restrict__ hs, const float* __restrict__ cosT,
    const float* __restrict__ sinT,
    u16* __restrict__ wqkvb, u16* __restrict__ wob, u16* __restrict__ hsb,
    u16* __restrict__ cosb, u16* __restrict__ sinb)
{
    const int i = blockIdx.x * 256 + threadIdx.x;
    const float* src; u16* dst;
    if (i < 524288)        { src = wq + (size_t)i * 8;             dst = wqkvb + (size_t)i * 8; }
    else if (i < 655360)   { src = wk + (size_t)(i - 524288) * 8;  dst = wqkvb + (size_t)i * 8; }
    else if (i < 786432)   { src = wv + (size_t)(i - 655360) * 8;  dst = wqkvb + (size_t)i * 8; }
    else if (i < 1310720)  { src = wo + (size_t)(i - 786432) * 8;  dst = wob + (size_t)(i - 786432) * 8; }
    else if (i < 1441792)  { src = hs + (size_t)(i - 1310720) * 8; dst = hsb + (size_t)(i - 1310720) * 8; }
    else if (i < 1475072)  { const int l = (i - 1441792) * 8;
                             src = cosT + (size_t)(l >> 6) * 128 + (l & 63); dst = cosb + l; }
    else                   { const int l = (i - 1475072) * 8;
                             src = sinT + (size_t)(l >> 6) * 128 + (l & 63); dst = sinb + l; }
    float4 a = *(const float4*)src;
    float4 b = *(const float4*)(src + 4);
    s16x8 v;
    v[0]=(short)f2bf(a.x); v[1]=(short)f2bf(a.y); v[2]=(short)f2bf(a.z); v[3]=(short)f2bf(a.w);
    v[4]=(short)f2bf(b.x); v[5]=(short)f2bf(b.y); v[6]=(short)f2bf(b.z); v[7]=(short)f2bf(b.w);
    *(s16x8*)dst = v;
}

// ---------------- mask pre-transpose: maskT[b][pos][q] bf16 ---------------
__global__ __launch_bounds__(256) void prep_mask(
    const float* __restrict__ mask, u16* __restrict__ maskT)
{
    __shared__ float T[64 * 65];
    const int pt = blockIdx.x % 65, b = blockIdx.x / 65;
    const int p0 = pt * 64;
    {
        const int q = threadIdx.x >> 2, pg = (threadIdx.x & 3) * 16;
        const float* src = mask + ((size_t)b * 64 + q) * TTOT + p0 + pg;
#pragma unroll
        for (int v4 = 0; v4 < 4; ++v4) {
            float4 v = *(const float4*)(src + v4 * 4);
            T[q * 65 + pg + v4 * 4 + 0] = fmaf(v.x, LOG2E, -MFIX);
            T[q * 65 + pg + v4 * 4 + 1] = fmaf(v.y, LOG2E, -MFIX);
            T[q * 65 + pg + v4 * 4 + 2] = fmaf(v.z, LOG2E, -MFIX);
            T[q * 65 + pg + v4 * 4 + 3] = fmaf(v.w, LOG2E, -MFIX);
        }
    }
    __syncthreads();
    {
        const int pos = threadIdx.x >> 2, qg = (threadIdx.x & 3) * 16;
        u16* dst = maskT + ((size_t)b * TTOT + p0 + pos) * 64 + qg;
#pragma unroll
        for (int h8 = 0; h8 < 2; ++h8) {
            s16x8 v;
#pragma unroll
            for (int je = 0; je < 8; ++je)
                v[je] = (short)f2bf(T[(qg + h8 * 8 + je) * 65 + pos]);
            *(s16x8*)(dst + h8 * 8) = v;
        }
    }
}

// ---------------- 64x64-tile GEMM core, bf16 inputs (padded LDS) ----------
__device__ __forceinline__ void gemm64_body(
    const u16* __restrict__ Ab, const u16* __restrict__ Bb,
    float* __restrict__ Cb, const int ldc, const int ldk, const int Klen,
    u16* Ash, u16* Bsh)
{
    const int tid = threadIdx.x, lane = tid & 63;
    const int w = tid >> 6, wm = w >> 1, wn = w & 1;
    const int l15 = lane & 15, l4 = lane >> 4;
    const int srow = tid >> 2, scol = (tid & 3) * 16;

    f32x4 acc[2][2];
#pragma unroll
    for (int i = 0; i < 2; ++i)
#pragma unroll
        for (int j = 0; j < 2; ++j) acc[i][j] = (f32x4){0.f, 0.f, 0.f, 0.f};

    const u16* ap = Ab + (size_t)srow * ldk + scol;
    const u16* bp = Bb + (size_t)srow * ldk + scol;
    s16x8 ra0 = *(const s16x8*)ap, ra1 = *(const s16x8*)(ap + 8);
    s16x8 rb0 = *(const s16x8*)bp, rb1 = *(const s16x8*)(bp + 8);
    __builtin_amdgcn_sched_barrier(0);

    for (int k0 = 0; k0 < Klen; k0 += 64) {
        __syncthreads();
        *(s16x8*)(Ash + srow * 72 + scol)     = ra0;
        *(s16x8*)(Ash + srow * 72 + scol + 8) = ra1;
        *(s16x8*)(Bsh + srow * 72 + scol)     = rb0;
        *(s16x8*)(Bsh + srow * 72 + scol + 8) = rb1;
        __syncthreads();
        if (k0 + 64 < Klen) {
            const u16* ap2 = ap + k0 + 64;
            const u16* bp2 = bp + k0 + 64;
            ra0 = *(const s16x8*)ap2; ra1 = *(const s16x8*)(ap2 + 8);
            rb0 = *(const s16x8*)bp2; rb1 = *(const s16x8*)(bp2 + 8);
            __builtin_amdgcn_sched_barrier(0);
        }
#pragma unroll
        for (int ks = 0; ks < 2; ++ks) {
            bf16x8 am[2], bb[2];
#pragma unroll
            for (int i = 0; i < 2; ++i) {
                am[i] = *(const bf16x8*)(Ash + (wm * 32 + i * 16 + l15) * 72 + ks * 32 + l4 * 8);
                bb[i] = *(const bf16x8*)(Bsh + (wn * 32 + i * 16 + l15) * 72 + ks * 32 + l4 * 8);
            }
#pragma unroll
            for (int i = 0; i < 2; ++i)
#pragma unroll
                for (int j = 0; j < 2; ++j)
                    acc[i][j] = mfma16(am[i], bb[j], acc[i][j]);
        }
    }

    float* Cw = Cb + (size_t)(wm * 32) * ldc + wn * 32;
#pragma unroll
    for (int i = 0; i < 2; ++i)
#pragma unroll
        for (int j = 0; j < 2; ++j)
#pragma unroll
            for (int r = 0; r < 4; ++r)
                Cw[(size_t)(i * 16 + l4 * 4 + r) * ldc + j * 16 + l15] = acc[i][j][r];
}

// QKV projection, split-K x4, XCD-chunked swizzle. 1D grid 1536.
__global__ __launch_bounds__(256) void gemm_qkv_sk(
    const u16* __restrict__ hsb, const u16* __restrict__ wqkvb,
    float* __restrict__ qkvp)
{
    __shared__ __align__(16) u16 Ash[64 * 72];
    __shared__ __align__(16) u16 Bsh[64 * 72];
    const int wid = (blockIdx.x & 7) * 192 + (blockIdx.x >> 3);
    const int y = wid >> 5, rem = wid & 31, kc = rem >> 3, x = rem & 7;
    const int koff = kc * 512;
    const u16* Ab = hsb + (size_t)x * 64 * HDIM + koff;
    const u16* Bb = wqkvb + (size_t)y * 64 * HDIM + koff;
    float* Cb = qkvp + (size_t)kc * 512 * 3072 + (size_t)x * 64 * 3072 + y * 64;
    gemm64_body(Ab, Bb, Cb, 3072, HDIM, 512, Ash, Bsh);
}

// Output projection, split-K x4, XCD-chunked swizzle. 1D grid 1024.
__global__ __launch_bounds__(256) void gemm_out_sk(
    const u16* __restrict__ attnb, const u16* __restrict__ wob,
    float* __restrict__ outp)
{
    __shared__ __align__(16) u16 Ash[64 * 72];
    __shared__ __align__(16) u16 Bsh[64 * 72];
    const int wid = (blockIdx.x & 7) * 128 + (blockIdx.x >> 3);
    const int y = wid >> 5, rem = wid & 31, kc = rem >> 3, x = rem & 7;
    const int koff = kc * 512;
    const u16* Ab = attnb + (size_t)x * 64 * HDIM + koff;
    const u16* Bb = wob + (size_t)y * 64 * HDIM + koff;
    float* Cb = outp + (size_t)kc * 512 * 2048 + (size_t)x * 64 * 2048 + y * 64;
    gemm64_body(Ab, Bb, Cb, 2048, HDIM, 512, Ash, Bsh);
}

// sum 4 partial chunks -> out (float4 per thread), deterministic.
__global__ __launch_bounds__(256) void reduce4(
    const float* __restrict__ p, float* __restrict__ out, const size_t chunk)
{
    const size_t i = ((size_t)blockIdx.x * 256 + threadIdx.x) * 4;
    float4 a = *(const float4*)(p + i);
    float4 b = *(const float4*)(p + i + chunk);
    float4 c = *(const float4*)(p + i + 2 * chunk);
    float4 d = *(const float4*)(p + i + 3 * chunk);
    float4 r;
    r.x = (a.x + b.x) + (c.x + d.x);
    r.y = (a.y + b.y) + (c.y + d.y);
    r.z = (a.z + b.z) + (c.z + d.z);
    r.w = (a.w + b.w) + (c.w + d.w);
    *(float4*)(out + i) = r;
}

// ---------------- RMSNorm+RoPE on in-register values (half-wave) ----------
__device__ __forceinline__ void norm_rope_vals(
    float2 xa, float2 xb, const float* __restrict__ wgt,
    const float* __restrict__ cosT, const float* __restrict__ sinT,
    int pos, int j, float outScale, u16* __restrict__ dst)
{
    float ss = xa.x * xa.x + xa.y * xa.y + xb.x * xb.x + xb.y * xb.y;
#pragma unroll
    for (int m = 1; m < 32; m <<= 1) ss += __shfl_xor(ss, m);
    const float rr = rsqrtf(ss * (1.0f / 128.0f) + 1e-6f);
    float2 wa = *(const float2*)(wgt + 2 * j);
    float2 wb = *(const float2*)(wgt + 2 * j + 64);
    float2 ca = *(const float2*)(cosT + (size_t)pos * 128 + 2 * j);
    float2 sa = *(const float2*)(sinT + (size_t)pos * 128 + 2 * j);
    const float nax = xa.x * rr * wa.x, nay = xa.y * rr * wa.y;
    const float nbx = xb.x * rr * wb.x, nby = xb.y * rr * wb.y;
    const float lox = (nax * ca.x - nbx * sa.x) * outScale;
    const float loy = (nay * ca.y - nby * sa.y) * outScale;
    const float hix = (nbx * ca.x + nax * sa.x) * outScale;
    const float hiy = (nby * ca.y + nay * sa.y) * outScale;
    ((u32*)dst)[j]      = pack2(lox, loy);
    ((u32*)dst)[j + 32] = pack2(hix, hiy);
}

// ---------------- fused split-K reduce + RMSNorm/RoPE/cast ----------------
__global__ __launch_bounds__(256) void finalize_qkv(
    const float* __restrict__ qkvp, const float* __restrict__ qw,
    const float* __restrict__ kw, const float* __restrict__ cosT,
    const float* __restrict__ sinT,
    u16* __restrict__ Qb, u16* __restrict__ knb, u16* __restrict__ vnb)
{
    const int unit = blockIdx.x * 8 + (threadIdx.x >> 5);
    const int j = threadIdx.x & 31;
    const int slot = unit % 24, bq = unit / 24;
    const int b = bq >> 6, q = bq & 63;
    const int col0 = (slot < 16) ? slot * 128
                   : (slot < 20) ? 2048 + (slot - 16) * 128
                                 : 2560 + (slot - 20) * 128;
    const float* base = qkvp + (size_t)bq * 3072 + col0;

    float2 xa = {0.f, 0.f}, xb = {0.f, 0.f};
#pragma unroll
    for (int kc = 0; kc < 4; ++kc) {
        const float* p = base + (size_t)kc * 512 * 3072;
        float2 a = *(const float2*)(p + 2 * j);
        float2 c = *(const float2*)(p + 2 * j + 64);
        xa.x += a.x; xa.y += a.y; xb.x += c.x; xb.y += c.y;
    }

    if (slot < 16) {
        norm_rope_vals(xa, xb, qw, cosT, sinT, CTX + q, j, QSCALE,
                       Qb + ((size_t)((b * 16 + slot) * 64 + q)) * 128);
    } else if (slot < 20) {
        norm_rope_vals(xa, xb, kw, cosT, sinT, CTX + q, j, 1.0f,
                       knb + ((size_t)((b * 4 + (slot - 16)) * 64 + q)) * 128);
    } else {
        u16* dst = vnb + ((size_t)((b * 4 + (slot - 20)) * 64 + q)) * 128;
        ((u32*)dst)[j]      = pack2(xa.x, xa.y);
        ((u32*)dst)[j + 32] = pack2(xb.x, xb.y);
    }
}

// ---------------- ctx V^T build: LDS-staged transpose + vnb tail ----------
__global__ __launch_bounds__(256) void build_ctx_v(
    const float* __restrict__ ctxv, const u16* __restrict__ vnb,
    u16* __restrict__ VtG)
{
    __shared__ __align__(16) float Vt[64 * 130];
    const int bid = blockIdx.x;
    if (bid < 2048) {
        const int pt = bid & 63, kv = (bid >> 6) & 3, b = bid >> 8;
        const int p0 = pt * 64;
        const float* src = ctxv + ((size_t)(b * 4096 + p0) * 4 + kv) * 128;
#pragma unroll
        for (int it = 0; it < 8; ++it) {
            const int g = it * 256 + threadIdx.x;
            const int row = g >> 5, c4 = (g & 31) * 4;
            *(float4*)(&Vt[row * 130 + c4]) = *(const float4*)(src + (size_t)row * 512 + c4);
        }
        __syncthreads();
        const int d = threadIdx.x & 127, half = threadIdx.x >> 7;
        u16* dst = VtG + ((size_t)(b * 4 + kv) * 128 + d) * TTOT + p0 + half * 32;
#pragma unroll
        for (int q8 = 0; q8 < 4; ++q8) {
            s16x8 v;
#pragma unroll
            for (int je = 0; je < 8; ++je)
                v[je] = (short)f2bf(Vt[(half * 32 + q8 * 8 + je) * 130 + d]);
            *(s16x8*)(dst + q8 * 8) = v;
        }
    } else {
        const int idx = bid - 2048;   // b*4+kv
        const u16* src = vnb + (size_t)idx * 64 * 128;
        u16* dstb = VtG + (size_t)idx * 128 * TTOT + 4096;
        const int d = threadIdx.x & 127, qh = threadIdx.x >> 7;
        u16* dst = dstb + (size_t)d * TTOT + qh * 32;
#pragma unroll
        for (int q8 = 0; q8 < 4; ++q8) {
            s16x8 v;
#pragma unroll
            for (int je = 0; je < 8; ++je)
                v[je] = (short)src[(size_t)(qh * 32 + q8 * 8 + je) * 128 + d];
            *(s16x8*)(dst + q8 * 8) = v;
        }
    }
}

// ---------------- flash attention: EXACT round-14 schedule (best: 56us) ---
// Round-16/17 lesson: "conflict-free" strides 132/68/36 u16 are 264/136/72
// BYTES -- not 16B multiples -> every s16x8 LDS access misaligned, b128 ops
// split. Counted conflicts fell but time rose. Keep 16B-aligned strides
// 136/72/40; the residual conflict count is inherent b128 multi-cycle cost.
template <int S>
__global__ __launch_bounds__(512, 2) void attn_partial(
    const u16* __restrict__ Qb, const float* __restrict__ ctxk,
    const float* __restrict__ knw, const u16* __restrict__ cosb,
    const u16* __restrict__ sinb, const u16* __restrict__ knb,
    const u16* __restrict__ VtG, const u16* __restrict__ maskT,
    u16* __restrict__ Opart, float* __restrict__ lsum)
{
    __shared__ __align__(16) u16 Ksh[2][64 * 136];   // K [pos][d], dbuf
    __shared__ __align__(16) u16 Vsh[2][128 * 72];   // V^T [d][pos], dbuf
    __shared__ __align__(16) u16 Msh[2][64 * 72];    // maskT tile [pos][q]
    __shared__ __align__(16) u16 Psh[8][32 * 40];    // per-wave P chunk

    const int s = blockIdx.x, kv = blockIdx.y, b = blockIdx.z;
    const int tid = threadIdx.x, lane = tid & 63, w = tid >> 6;
    const int h = kv * 4 + (w >> 1);
    const int qh = w & 1, qbase = qh * 32;
    const int l15 = lane & 15, l4 = lane >> 4;
    const int t0 = (NTILES * s) / S, t1 = (NTILES * (s + 1)) / S;

    const int krow = tid >> 3, kg8 = (tid & 7) * 8;
    const int vr = tid >> 3, vc8 = (tid & 7) * 8;
    const int mpos = tid >> 3, mq8 = (tid & 7) * 8;

    const float4 w0 = *(const float4*)(knw + kg8);
    const float4 w1 = *(const float4*)(knw + kg8 + 4);
    const float4 w2 = *(const float4*)(knw + kg8 + 64);
    const float4 w3 = *(const float4*)(knw + kg8 + 68);

    bf16x8 aq[2][4];
    {
        const u16* qb = Qb + ((size_t)((b * 16 + h) * 64 + qbase)) * 128;
#pragma unroll
        for (int mt = 0; mt < 2; ++mt)
#pragma unroll
            for (int ks = 0; ks < 4; ++ks)
                aq[mt][ks] = *(const bf16x8*)(qb + (mt * 16 + l15) * 128 + ks * 32 + l4 * 8);
    }

    bf16x8 bones;   // col-0 ones -> P row sums via MFMA
    {
        __bf16 e = (l15 == 0) ? (__bf16)1.0f : (__bf16)0.0f;
#pragma unroll
        for (int i = 0; i < 8; ++i) bones[i] = e;
    }

    f32x4 o[2][8], ol[2];
#pragma unroll
    for (int mt = 0; mt < 2; ++mt) {
        ol[mt] = (f32x4){0.f, 0.f, 0.f, 0.f};
#pragma unroll
        for (int nt = 0; nt < 8; ++nt) o[mt][nt] = (f32x4){0.f, 0.f, 0.f, 0.f};
    }

    const u16* Kn    = knb + (size_t)(b * 4 + kv) * 64 * 128;
    const u16* Vbase = VtG + (size_t)(b * 4 + kv) * 128 * TTOT;
    const u16* mrow  = maskT + (size_t)b * TTOT * 64;
    u16* P = Psh[w];

    float4 rx0, rx1, rx2, rx3;          // raw K f32 (tiles 0..63)
    s16x8 rcs, rsn;                     // bf16 cos/sin slice
    s16x8 rkn0, rkn1;                   // knb bf16 (tile 64)
    s16x8 rv0, rv1, rm;
    int tin = -1;

    auto ld = [&](int t) {
        const int p = t * 64;
        if (t < 64) {
            const float* kp_ = ctxk + (((size_t)(b * 4096 + p + krow)) * 4 + kv) * 128 + kg8;
            rx0 = *(const float4*)kp_;        rx1 = *(const float4*)(kp_ + 4);
            rx2 = *(const float4*)(kp_ + 64); rx3 = *(const float4*)(kp_ + 68);
            rcs = *(const s16x8*)(cosb + (size_t)(p + krow) * 64 + kg8);
            rsn = *(const s16x8*)(sinb + (size_t)(p + krow) * 64 + kg8);
        } else {
            const u16* kp2 = Kn + (size_t)krow * 128 + kg8;
            rkn0 = *(const s16x8*)kp2;
            rkn1 = *(const s16x8*)(kp2 + 64);
        }
        rv0 = *(const s16x8*)(Vbase + (size_t)vr * TTOT + p + vc8);
        rv1 = *(const s16x8*)(Vbase + (size_t)(vr + 64) * TTOT + p + vc8);
        rm  = *(const s16x8*)(mrow + (size_t)(p + mpos) * 64 + mq8);
        tin = t;
        __builtin_amdgcn_sched_barrier(0);   // pin load issue here
    };
    auto st = [&](int buf) {
        if (tin < 64) {
            float ss = rx0.x*rx0.x + rx0.y*rx0.y + rx0.z*rx0.z + rx0.w*rx0.w
                     + rx1.x*rx1.x + rx1.y*rx1.y + rx1.z*rx1.z + rx1.w*rx1.w
                     + rx2.x*rx2.x + rx2.y*rx2.y + rx2.z*rx2.z + rx2.w*rx2.w
                     + rx3.x*rx3.x + rx3.y*rx3.y + rx3.z*rx3.z + rx3.w*rx3.w;
            ss += __shfl_xor(ss, 1);
            ss += __shfl_xor(ss, 2);
            ss += __shfl_xor(ss, 4);
            const float rr = rsqrtf(ss * (1.0f / 128.0f) + 1e-6f);
            s16x8 klo, khi;
#define KROPE(i, xl, xh, wl, wh)                                     \
            {                                                        \
                const float nlo = xl * rr * wl, nhi = xh * rr * wh;  \
                const float c = bf2f((u16)rcs[i]), sn = bf2f((u16)rsn[i]); \
                klo[i] = (short)f2bf(nlo * c - nhi * sn);            \
                khi[i] = (short)f2bf(nhi * c + nlo * sn);            \
            }
            KROPE(0, rx0.x, rx2.x, w0.x, w2.x)
            KROPE(1, rx0.y, rx2.y, w0.y, w2.y)
            KROPE(2, rx0.z, rx2.z, w0.z, w2.z)
            KROPE(3, rx0.w, rx2.w, w0.w, w2.w)
            KROPE(4, rx1.x, rx3.x, w1.x, w3.x)
            KROPE(5, rx1.y, rx3.y, w1.y, w3.y)
            KROPE(6, rx1.z, rx3.z, w1.z, w3.z)
            KROPE(7, rx1.w, rx3.w, w1.w, w3.w)
#undef KROPE
            *(s16x8*)(Ksh[buf] + krow * 136 + kg8)      = klo;
            *(s16x8*)(Ksh[buf] + krow * 136 + 64 + kg8) = khi;
        } else {
            *(s16x8*)(Ksh[buf] + krow * 136 + kg8)      = rkn0;
            *(s16x8*)(Ksh[buf] + krow * 136 + 64 + kg8) = rkn1;
        }
        *(s16x8*)(Vsh[buf] + vr * 72 + vc8) = rv0;
        *(s16x8*)(Vsh[buf] + (vr + 64) * 72 + vc8) = rv1;
        *(s16x8*)(Msh[buf] + mpos * 72 + mq8) = rm;
    };

    // prologue
    ld(t0);
    st(0);
    __syncthreads();
    if (t0 + 1 < t1) ld(t0 + 1);

    int cur = 0;
    for (int t = t0; t < t1; ++t) {
        // ---- compute tile t from buf[cur] ----
        f32x4 sc[2][4];
#pragma unroll
        for (int mt = 0; mt < 2; ++mt)
#pragma unroll
            for (int nt = 0; nt < 4; ++nt) sc[mt][nt] = (f32x4){0.f, 0.f, 0.f, 0.f};
        __builtin_amdgcn_s_setprio(1);
#pragma unroll
        for (int nt = 0; nt < 4; ++nt) {
#pragma unroll
            for (int ks = 0; ks < 4; ++ks) {
                bf16x8 bk = *(const bf16x8*)(Ksh[cur] + (nt * 16 + l15) * 136 + ks * 32 + l4 * 8);
                sc[0][nt] = mfma16(aq[0][ks], bk, sc[0][nt]);
                sc[1][nt] = mfma16(aq[1][ks], bk, sc[1][nt]);
            }
        }
        __builtin_amdgcn_s_setprio(0);

        // fixed-max softmax: p = exp2(sc + msh); msh pre-folded bf16 [pos][q]
#pragma unroll
        for (int mt = 0; mt < 2; ++mt) {
#pragma unroll
            for (int nt = 0; nt < 4; ++nt) {
                u16x4 m4 = *(const u16x4*)(Msh[cur] + (nt * 16 + l15) * 72 + qbase + mt * 16 + l4 * 4);
#pragma unroll
                for (int r = 0; r < 4; ++r)
                    sc[mt][nt][r] = exp2f(sc[mt][nt][r] + bf2f(m4[r]));
            }
        }

        // O += P V ; l += P 1
#pragma unroll
        for (int ks = 0; ks < 2; ++ks) {
#pragma unroll
            for (int mt = 0; mt < 2; ++mt)
#pragma unroll
                for (int r = 0; r < 4; ++r) {
                    P[(mt * 16 + l4 * 4 + r) * 40 + l15]      = f2bf(sc[mt][ks * 2 + 0][r]);
                    P[(mt * 16 + l4 * 4 + r) * 40 + 16 + l15] = f2bf(sc[mt][ks * 2 + 1][r]);
                }
            bf16x8 ap0 = *(const bf16x8*)(P + (l15) * 40 + l4 * 8);
            bf16x8 ap1 = *(const bf16x8*)(P + (16 + l15) * 40 + l4 * 8);
            __builtin_amdgcn_s_setprio(1);
#pragma unroll
            for (int nt = 0; nt < 8; ++nt) {
                bf16x8 bv = *(const bf16x8*)(Vsh[cur] + (nt * 16 + l15) * 72 + ks * 32 + l4 * 8);
                o[0][nt] = mfma16(ap0, bv, o[0][nt]);
                o[1][nt] = mfma16(ap1, bv, o[1][nt]);
            }
            ol[0] = mfma16(ap0, bones, ol[0]);
            ol[1] = mfma16(ap1, bones, ol[1]);
            __builtin_amdgcn_s_setprio(0);
        }

        // ---- stage tile t+1 into buf[cur^1]; prefetch t+2 ----
        if (t + 1 < t1) st(cur ^ 1);      // KROPE overlapped, off critical path
        __syncthreads();
        if (t + 2 < t1) ld(t + 2);
        cur ^= 1;
    }

    // coalesced epilogue: Opart chunk per (b,h,s) = [qh][mt][nt][lane][r] u16
    {
        u16* ob = Opart + ((size_t)((b * 16 + h) * S + s)) * 8192;
#pragma unroll
        for (int mt = 0; mt < 2; ++mt)
#pragma unroll
            for (int nt = 0; nt < 8; ++nt) {
                u16x4 v;
#pragma unroll
                for (int r = 0; r < 4; ++r) v[r] = f2bf(o[mt][nt][r]);
                *(u16x4*)(ob + (((qh * 2 + mt) * 8 + nt) * 64 + lane) * 4) = v;
            }
        if (l15 == 0) {
#pragma unroll
            for (int mt = 0; mt < 2; ++mt)
#pragma unroll
                for (int r = 0; r < 4; ++r) {
                    const int q = qbase + mt * 16 + l4 * 4 + r;
                    lsum[((size_t)((b * 16 + h) * 64 + q)) * S + s] = ol[mt][r];
                }
        }
    }
}

// ---------------- merge splits -> attn (B,K,NH*HD) bf16 -------------------
// 4-way nt-split: grid 256 (was 64; 0.25 blk/CU moving ~19MB was
// launch-starved). Each wave handles nt in {ng*2, ng*2+1}.
template <int S>
__global__ __launch_bounds__(256) void merge_kernel(
    const u16* __restrict__ Opart, const float* __restrict__ lsum, u16* __restrict__ attnb)
{
    const int wid = blockIdx.x * 4 + (threadIdx.x >> 6);   // ((b*16+h)*2+qh)*4+ng
    const int lane = threadIdx.x & 63;
    const int l15 = lane & 15, l4 = lane >> 4;
    const int ng = wid & 3;
    const int qh = (wid >> 2) & 1, bh = wid >> 3;
    const int h = bh & 15, b = bh >> 4;

    float L = 0.f;
    {
        const float* lr = lsum + ((size_t)bh * 64 + qh * 32 + (lane & 31)) * S;
#pragma unroll
        for (int s2 = 0; s2 < S; ++s2) L += lr[s2];
    }
    const float invL = 1.0f / L;

    float acc[2][2][4];
#pragma unroll
    for (int mt = 0; mt < 2; ++mt)
#pragma unroll
        for (int ntl = 0; ntl < 2; ++ntl)
#pragma unroll
            for (int r = 0; r < 4; ++r) acc[mt][ntl][r] = 0.f;

    for (int s2 = 0; s2 < S; ++s2) {
        const u16* ob = Opart + ((size_t)(bh * S + s2)) * 8192;
#pragma unroll
        for (int mt = 0; mt < 2; ++mt)
#pragma unroll
            for (int ntl = 0; ntl < 2; ++ntl) {
                const int nt = ng * 2 + ntl;
                u16x4 v = *(const u16x4*)(ob + (((qh * 2 + mt) * 8 + nt) * 64 + lane) * 4);
#pragma unroll
                for (int r = 0; r < 4; ++r) acc[mt][ntl][r] += bf2f(v[r]);
            }
    }

#pragma unroll
    for (int mt = 0; mt < 2; ++mt)
#pragma unroll
        for (int r = 0; r < 4; ++r) {
            const float wl = __shfl(invL, mt * 16 + l4 * 4 + r);
            const int q = qh * 32 + mt * 16 + l4 * 4 + r;
            u16* dst = attnb + (size_t)(b * 64 + q) * 2048 + h * 128;
#pragma unroll
            for (int ntl = 0; ntl < 2; ++ntl) {
                const int nt = ng * 2 + ntl;
                dst[nt * 16 + l15] = f2bf(acc[mt][ntl][r] * wl);
            }
        }
}

// ---------------- launch ----------------
extern "C" void kernel_launch(void* const* d_in, const int* in_sizes, int n_in,
                              void* d_out, int out_size, void* d_ws, size_t ws_size,
                              hipStream_t stream)
{
    (void)in_sizes; (void)n_in; (void)out_size; (void)ws_size;
    const float* hs   = (const float*)d_in[0];
    const float* ctxk = (const float*)d_in[1];
    const float* ctxv = (const float*)d_in[2];
    const float* mask = (const float*)d_in[3];
    const float* cosT = (const float*)d_in[4];
    const float* sinT = (const float*)d_in[5];
    const float* wq   = (const float*)d_in[6];
    const float* wk   = (const float*)d_in[7];
    const float* wv   = (const float*)d_in[8];
    const float* wo   = (const float*)d_in[9];
    const float* qnw  = (const float*)d_in[10];
    const float* knw  = (const float*)d_in[11];

    const int S = 8;

    char* ws = (char*)d_ws;
    size_t off = 0;
    auto carve = [&](size_t bytes) -> void* {
        void* p = ws + off;
        off += (bytes + 255) & ~(size_t)255;
        return p;
    };
    u16*   Qb    = (u16*)carve((size_t)BB * NH * 64 * 128 * 2);         // 2.1 MB
    u16*   VtG   = (u16*)carve((size_t)BB * NKV * TTOT * 128 * 2);      // 34.1 MB
    u16*   Opart = (u16*)carve((size_t)BB * NH * S * 8192 * 2);         // 16.8 MB
    float* lsumb = (float*)carve((size_t)BB * NH * 64 * S * 4);         // 0.26 MB
    u16*   attnb = (u16*)carve((size_t)512 * 2048 * 2);                 // 2.1 MB
    u16*   wob   = (u16*)carve((size_t)2048 * 2048 * 2);                // 8.4 MB
    u16*   wqkvb = (u16*)carve((size_t)3072 * 2048 * 2);                // 12.6 MB
    u16*   knb   = (u16*)carve((size_t)BB * NKV * 64 * 128 * 2);        // 0.52 MB
    u16*   vnb   = (u16*)carve((size_t)BB * NKV * 64 * 128 * 2);        // 0.52 MB
    u16*   maskT = (u16*)carve((size_t)BB * TTOT * 64 * 2);             // 4.3 MB
    u16*   cosb  = (u16*)carve((size_t)TTOT * 64 * 2);                  // 0.53 MB
    u16*   sinb  = (u16*)carve((size_t)TTOT * 64 * 2);                  // 0.53 MB
    // ~82.8 MB. Time-multiplexed aliases (stream-ordered liveness):
    float* qkvp = (float*)VtG;    // qkv split-K partials; dead before build_ctx_v
    u16*   hsb  = (u16*)Opart;    // bf16 hs; dead before attn_partial
    float* outp = (float*)Opart;  // out partials; Opart dead after merge

    // 1) cast weights/activations + bf16 cos/sin half-tables; fold mask
    cast_all<<<5892, 256, 0, stream>>>(wq, wk, wv, wo, hs, cosT, sinT,
                                       wqkvb, wob, hsb, cosb, sinb);
    prep_mask<<<520, 256, 0, stream>>>(mask, maskT);
    // 2) QKV projection (bf16, split-K x4, XCD swizzle)
    gemm_qkv_sk<<<1536, 256, 0, stream>>>(hsb, wqkvb, qkvp);
    // 3) fused reduce + RMSNorm/RoPE/cast -> Qb, k-noise, v-noise
    finalize_qkv<<<1536, 256, 0, stream>>>(qkvp, qnw, knw, cosT, sinT, Qb, knb, vnb);
    // 4) ctx V^T (LDS-staged transpose); K build is FUSED into attn
    build_ctx_v<<<2080, 256, 0, stream>>>(ctxv, vnb, VtG);
    // 5) flash attention (round-14 schedule) + 4-way-split merge
    attn_partial<8><<<dim3(8, NKV, BB), 512, 0, stream>>>(
        Qb, ctxk, knw, cosb, sinb, knb, VtG, maskT, Opart, lsumb);
    merge_kernel<8><<<256, 256, 0, stream>>>(Opart, lsumb, attnb);
    // 6) output projection (bf16, split-K x4, XCD swizzle) -> reduce
    gemm_out_sk<<<1024, 256, 0, stream>>>(attnb, wob, outp);
    reduce4<<<1024, 256, 0, stream>>>(outp, (float*)d_out, (size_t)512 * 2048);
}